// Round 9
// baseline (174.368 us; speedup 1.0000x reference)
//
#include <hip/hip_runtime.h>
#include <hip/hip_bf16.h>

#define S_DIM 2048
#define D_DIM 512
#define B_DIM 8
#define SCALE 0.02209708691207961f  // 1/sqrt(2048)

typedef __hip_bfloat16 bf16;
typedef short bf16x8 __attribute__((ext_vector_type(8)));
typedef float f32x4 __attribute__((ext_vector_type(4)));

__device__ __forceinline__ unsigned short f2b(float f) {
  __hip_bfloat16 h = __float2bfloat16(f);
  return __builtin_bit_cast(unsigned short, h);
}
__device__ __forceinline__ float b2f(unsigned short s) {
  return __bfloat162float(__builtin_bit_cast(__hip_bfloat16, s));
}

__device__ __forceinline__ void load_lds16(const void* g, void* l) {
  __builtin_amdgcn_global_load_lds((const __attribute__((address_space(1))) void*)g,
                                   (__attribute__((address_space(3))) void*)l, 16, 0, 0);
}

// ---------------- kernel matrix f32 -> bf16 ----------------
__global__ void convert_k(const float* __restrict__ in, bf16* __restrict__ out, int n8) {
  int i = blockIdx.x * blockDim.x + threadIdx.x;
  if (i >= n8) return;
  const float4* p = (const float4*)in;
  float4 a = p[2 * i], b = p[2 * i + 1];
  bf16x8 r;
  r[0] = f2b(a.x); r[1] = f2b(a.y); r[2] = f2b(a.z); r[3] = f2b(a.w);
  r[4] = f2b(b.x); r[5] = f2b(b.y); r[6] = f2b(b.z); r[7] = f2b(b.w);
  ((bf16x8*)out)[i] = r;
}

// ---------------- transpose x1,x2 (S,D) f32 -> (D,S) bf16, 64x64 tiles ----------------
__global__ void tr_f2b64(const float* __restrict__ x1, const float* __restrict__ x2,
                         bf16* __restrict__ out) {
  __shared__ unsigned short t[64][66];
  const int z = blockIdx.z;
  const float* in = (z < 8 ? x1 : x2) + (size_t)(z & 7) * (S_DIM * D_DIM);
  bf16* ob = out + (size_t)z * (size_t)(D_DIM * S_DIM);
  const int r0 = blockIdx.y * 64;
  const int c0 = blockIdx.x * 64;
  const int tid = threadIdx.x;
  const int lr = tid >> 6, lc = tid & 63;
#pragma unroll
  for (int i = 0; i < 16; i++) {
    int r = i * 4 + lr;
    t[lc][r] = f2b(in[(size_t)(r0 + r) * D_DIM + c0 + lc]);
  }
  __syncthreads();
  const int dl = tid >> 4, tq = tid & 15;
#pragma unroll
  for (int j = 0; j < 4; j++) {
    int d = j * 16 + dl;
    const unsigned short* p = &t[d][tq * 4];
    uint2 u;
    u.x = (unsigned)p[0] | ((unsigned)p[1] << 16);
    u.y = (unsigned)p[2] | ((unsigned)p[3] << 16);
    *(uint2*)(ob + (size_t)(c0 + d) * S_DIM + r0 + tq * 4) = u;
  }
}

// ---------------- transpose h1n (S,D) bf16 -> (D,S) bf16, 64x64 tiles ----------------
__global__ void tr_b2b64(const bf16* __restrict__ in, bf16* __restrict__ out) {
  __shared__ unsigned short t[64][66];
  const int z = blockIdx.z;
  const bf16* ib = in + (size_t)z * (S_DIM * D_DIM);
  bf16* ob = out + (size_t)z * (S_DIM * D_DIM);
  const int r0 = blockIdx.y * 64;
  const int c0 = blockIdx.x * 64;
  const int tid = threadIdx.x;
  const int lr = tid >> 5, cp = tid & 31;
#pragma unroll
  for (int i = 0; i < 8; i++) {
    int r = i * 8 + lr;
    unsigned v = *(const unsigned*)(ib + (size_t)(r0 + r) * D_DIM + c0 + cp * 2);
    t[cp * 2][r] = (unsigned short)(v & 0xffff);
    t[cp * 2 + 1][r] = (unsigned short)(v >> 16);
  }
  __syncthreads();
  const int dl = tid >> 4, tq = tid & 15;
#pragma unroll
  for (int j = 0; j < 4; j++) {
    int d = j * 16 + dl;
    const unsigned short* p = &t[d][tq * 4];
    uint2 u;
    u.x = (unsigned)p[0] | ((unsigned)p[1] << 16);
    u.y = (unsigned)p[2] | ((unsigned)p[3] << 16);
    *(uint2*)(ob + (size_t)(c0 + d) * S_DIM + r0 + tq * 4) = u;
  }
}

// ---------------- h-GEMM, 8-phase v3 (spill-free): H[item] = A @ X[item]^T ------------
// 256x256, BK=64, 8 waves (2m x 4n; per-wave 128x64). LDS 128KB:
//   A[buf=t&1][half] 4x16KB @0 (half h = global rows h*128..h*128+127),
//   B[buf][half]     4x16KB @64KB.
// Quadrant order (mh,nh)=(0,0)(0,1)(1,0)(1,1): hold ONE af[4][2] (32 VGPR) across 2
// phases + bfr[2][2] (16) re-read per phase => 48 held frag VGPRs (R4-equal, no spill).
// Phase = {ds_reads, stage 1 half-tile, bar, lgkmcnt(0), setprio1, 16 MFMA, setprio0, bar}.
// Stages: P1:B0(t+1) P2:B1(t+1) P3:A0(t+2) P4:A1(t+2)+vmcnt(4) (counted; 0 at tail).
// Swizzle (R5-verified 0 conflicts): LDS[r][slot16B] = G[r][slot ^ (r&7)]; read XORs same.
__global__ __launch_bounds__(512, 1) void gemm_h(
    const bf16* __restrict__ A, const bf16* __restrict__ X, bf16* __restrict__ H) {
  extern __shared__ char smem[];
  const int pid = blockIdx.x;
  const int mt = pid & 7;          // XCD-pinned A panel
  const int r_ = pid >> 3;
  const int ntile = r_ & 1;
  const int item = r_ >> 1;        // 0..15
  const int m0 = mt * 256, n0 = ntile * 256;
  const bf16* Asrc = A + (size_t)m0 * S_DIM;
  const bf16* Bsrc = X + (size_t)item * (D_DIM * S_DIM) + (size_t)n0 * S_DIM;
  bf16* Hi = H + (size_t)item * (S_DIM * D_DIM);

  const int tid = threadIdx.x;
  const int w = tid >> 6, L = tid & 63;
  const int l15 = L & 15, lhi = L >> 4;
  const int wr = w >> 2, wn = w & 3;

  // staging sources (pre-swizzled): row h*128 + w*16 + ld*8 + (L>>3), slot (L&7)^(L>>3)
  const int sr8 = L >> 3;
  const int sslot = ((L & 7) ^ sr8) * 8;
  const bf16* pA[2][2];
  const bf16* pB[2][2];
#pragma unroll
  for (int h = 0; h < 2; h++)
#pragma unroll
    for (int ld = 0; ld < 2; ld++) {
      pA[h][ld] = Asrc + (size_t)(h * 128 + w * 16 + ld * 8 + sr8) * S_DIM + sslot;
      pB[h][ld] = Bsrc + (size_t)(h * 128 + w * 16 + ld * 8 + sr8) * S_DIM + sslot;
    }

  auto stageA = [&](int t2, int half) {
    char* d = smem + ((t2 & 1) << 15) + (half << 14) + w * 2048;
#pragma unroll
    for (int ld = 0; ld < 2; ld++) load_lds16(pA[half][ld] + t2 * 64, d + ld * 1024);
  };
  auto stageB = [&](int t2, int half) {
    char* d = smem + 65536 + ((t2 & 1) << 15) + (half << 14) + w * 2048;
#pragma unroll
    for (int ld = 0; ld < 2; ld++) load_lds16(pB[half][ld] + t2 * 64, d + ld * 1024);
  };

  const int xsw = l15 & 7;
  const int cK0 = (lhi ^ xsw) << 4;
  const int cK1 = ((4 + lhi) ^ xsw) << 4;

  bf16x8 af[4][2], bfr[2][2];
  // wave wr's A rows live in half wr; within: mh*64 + m*16 + l15
  auto readA = [&](int buf, int mh) {
    const char* base = smem + (buf << 15) + (wr << 14) + mh * 8192 + l15 * 128;
#pragma unroll
    for (int m = 0; m < 4; m++) {
      af[m][0] = *(const bf16x8*)(base + m * 2048 + cK0);
      af[m][1] = *(const bf16x8*)(base + m * 2048 + cK1);
    }
  };
  // wave wn's B rows live in half wn>>1; within: (wn&1)*64 + nh*32 + n*16 + l15
  auto readB = [&](int buf, int nh) {
    const char* base = smem + 65536 + (buf << 15) + ((wn >> 1) << 14) + (wn & 1) * 8192 +
                       nh * 4096 + l15 * 128;
#pragma unroll
    for (int n = 0; n < 2; n++) {
      bfr[n][0] = *(const bf16x8*)(base + n * 2048 + cK0);
      bfr[n][1] = *(const bf16x8*)(base + n * 2048 + cK1);
    }
  };

  f32x4 acc[8][4];
#pragma unroll
  for (int m = 0; m < 8; m++)
#pragma unroll
    for (int n = 0; n < 4; n++) acc[m][n] = (f32x4){0, 0, 0, 0};

  auto mfmaQ = [&](int mh, int nh) {
    __builtin_amdgcn_s_setprio(1);
#pragma unroll
    for (int kk = 0; kk < 2; kk++)
#pragma unroll
      for (int m = 0; m < 4; m++)
#pragma unroll
        for (int n = 0; n < 2; n++)
          acc[mh * 4 + m][nh * 2 + n] = __builtin_amdgcn_mfma_f32_16x16x32_bf16(
              bfr[n][kk], af[m][kk], acc[mh * 4 + m][nh * 2 + n], 0, 0, 0);
    __builtin_amdgcn_s_setprio(0);
  };
  auto bar = [&] {
    asm volatile("" ::: "memory");
    __builtin_amdgcn_s_barrier();
    asm volatile("" ::: "memory");
  };
  auto lgkm0 = [&] { asm volatile("s_waitcnt lgkmcnt(0)" ::: "memory"); };

  const int NT = 32;
  // prologue: tile0 (8 loads) + A halves of tile1 (4); vmcnt(4) keeps A(1) in flight
  stageA(0, 0); stageA(0, 1); stageB(0, 0); stageB(0, 1);
  stageA(1, 0); stageA(1, 1);
  asm volatile("s_waitcnt vmcnt(4)" ::: "memory");
  bar();

#pragma unroll 1
  for (int t = 0; t < NT; ++t) {
    const int buf = t & 1;
    const bool s1 = (t + 1 < NT);
    const bool s2 = (t + 2 < NT);
    // P1: af<-mh0 (8 reads), bfr<-nh0 (4); stage B0(t+1); MFMA q(0,0)
    readA(buf, 0); readB(buf, 0);
    if (s1) stageB(t + 1, 0);
    bar(); lgkm0(); mfmaQ(0, 0); bar();
    // P2: bfr<-nh1 (4); stage B1(t+1); MFMA q(0,1)
    readB(buf, 1);
    if (s1) stageB(t + 1, 1);
    bar(); lgkm0(); mfmaQ(0, 1); bar();
    // P3: af<-mh1 (8), bfr<-nh0 (4); stage A0(t+2); MFMA q(1,0)
    readA(buf, 1); readB(buf, 0);
    if (s2) stageA(t + 2, 0);
    bar(); lgkm0(); mfmaQ(1, 0); bar();
    // P4: bfr<-nh1 (4); stage A1(t+2); MFMA q(1,1); counted vmcnt
    readB(buf, 1);
    if (s2) stageA(t + 2, 1);
    bar(); lgkm0(); mfmaQ(1, 1);
    if (s2) asm volatile("s_waitcnt vmcnt(4)" ::: "memory");
    else    asm volatile("s_waitcnt vmcnt(0)" ::: "memory");
    bar();
  }

  // swapped-operand C layout -> 8B packed stores
#pragma unroll
  for (int m = 0; m < 8; m++) {
    int grow = m0 + wr * 128 + m * 16 + l15;
#pragma unroll
    for (int n = 0; n < 4; n++) {
      int gcol = n0 + wn * 64 + n * 16 + lhi * 4;
      uint2 u;
      u.x = ((unsigned)f2b(acc[m][n][1]) << 16) | f2b(acc[m][n][0]);
      u.y = ((unsigned)f2b(acc[m][n][3]) << 16) | f2b(acc[m][n][2]);
      *(uint2*)(Hi + (size_t)grow * D_DIM + gcol) = u;
    }
  }
}

// ---------------- score GEMM (R4-verbatim): E = exp(SCALE*h1 h2^T), lower-tri 256 ----
__global__ __launch_bounds__(512, 2) void gemm_score(
    const bf16* __restrict__ H1, const bf16* __restrict__ H2,
    bf16* __restrict__ E, float* __restrict__ rowsum) {
  extern __shared__ char smem[];
  const int pid = blockIdx.x;
  const int b = pid & 7;
  const int tri = pid >> 3;
  int mt = (int)((sqrtf(8.0f * (float)tri + 1.0f) - 1.0f) * 0.5f);
  while ((mt + 1) * (mt + 2) / 2 <= tri) mt++;
  while (mt * (mt + 1) / 2 > tri) mt--;
  const int nt = tri - mt * (mt + 1) / 2;
  const int m0 = mt * 256, n0 = nt * 256;
  const bool diag = (mt == nt);
  const bf16* Ab = H1 + (size_t)b * S_DIM * D_DIM;
  const bf16* Bb = H2 + (size_t)b * S_DIM * D_DIM;
  bf16* Eb = E + (size_t)b * S_DIM * S_DIM;
  float* rs = rowsum + b * S_DIM;

  const int tid = threadIdx.x;
  const int w = tid >> 6, L = tid & 63;
  const int l15 = L & 15, lhi = L >> 4;
  const int wr = w >> 2, wn = w & 3;

  const int srow = tid >> 2;
  const int sslot = ((tid & 3) ^ ((tid >> 3) & 3)) * 8;
  const bf16* pA[2];
  const bf16* pB[2];
#pragma unroll
  for (int ld = 0; ld < 2; ld++) {
    pA[ld] = Ab + (size_t)(m0 + ld * 128 + srow) * D_DIM + sslot;
    pB[ld] = Bb + (size_t)(n0 + ld * 128 + srow) * D_DIM + sslot;
  }

  char* A0 = smem;          char* A1 = smem + 16384;  char* A2 = smem + 32768;
  char* B0 = smem + 49152;  char* B1 = smem + 65536;  char* B2 = smem + 81920;

  auto stage = [&](int t2, char* dA, char* dB) {
#pragma unroll
    for (int ld = 0; ld < 2; ld++)
      load_lds16(pA[ld] + t2 * 32, dA + ld * 8192 + w * 1024);
#pragma unroll
    for (int ld = 0; ld < 2; ld++)
      load_lds16(pB[ld] + t2 * 32, dB + ld * 8192 + w * 1024);
  };

  const int xo = (lhi ^ ((l15 >> 1) & 3)) << 4;
  int offA[8], offB[4];
#pragma unroll
  for (int m = 0; m < 8; m++) offA[m] = (wr * 128 + m * 16 + l15) * 64 + xo;
#pragma unroll
  for (int n = 0; n < 4; n++) offB[n] = (wn * 64 + n * 16 + l15) * 64 + xo;

  f32x4 acc[8][4];
#pragma unroll
  for (int m = 0; m < 8; m++)
#pragma unroll
    for (int n = 0; n < 4; n++) acc[m][n] = (f32x4){0, 0, 0, 0};

  stage(0, A0, B0);
  stage(1, A1, B1);

#pragma unroll 1
  for (int t = 0; t < 16; ++t) {
    if (t < 15) asm volatile("s_waitcnt vmcnt(4)" ::: "memory");
    else        asm volatile("s_waitcnt vmcnt(0)" ::: "memory");
    __builtin_amdgcn_s_barrier();
    asm volatile("" ::: "memory");
    if (t < 14) stage(t + 2, A2, B2);

    bf16x8 af[8], bfv[4];
#pragma unroll
    for (int m = 0; m < 8; m++) af[m] = *(const bf16x8*)(A0 + offA[m]);
#pragma unroll
    for (int n = 0; n < 4; n++) bfv[n] = *(const bf16x8*)(B0 + offB[n]);
    __builtin_amdgcn_s_setprio(1);
#pragma unroll
    for (int m = 0; m < 8; m++)
#pragma unroll
      for (int n = 0; n < 4; n++)
        acc[m][n] = __builtin_amdgcn_mfma_f32_16x16x32_bf16(bfv[n], af[m], acc[m][n], 0, 0, 0);
    __builtin_amdgcn_s_setprio(0);

    char* tA = A0; A0 = A1; A1 = A2; A2 = tA;
    char* tB = B0; B0 = B1; B1 = B2; B2 = tB;
  }

#pragma unroll
  for (int m = 0; m < 8; m++) {
    int sg = m0 + wr * 128 + m * 16 + l15;
    float rp = 0.0f;
#pragma unroll
    for (int n = 0; n < 4; n++) {
      int tg0 = n0 + wn * 64 + n * 16 + lhi * 4;
      unsigned short e[4];
#pragma unroll
      for (int r = 0; r < 4; r++) {
        float v = (!diag || (tg0 + r) <= sg) ? __expf(acc[m][n][r] * SCALE) : 0.0f;
        e[r] = f2b(v);
        rp += b2f(e[r]);
      }
      uint2 u;
      u.x = ((unsigned)e[1] << 16) | e[0];
      u.y = ((unsigned)e[3] << 16) | e[2];
      *(uint2*)(Eb + (size_t)sg * S_DIM + tg0) = u;
    }
    rp += __shfl_xor(rp, 16);
    rp += __shfl_xor(rp, 32);
    if (lhi == 0) atomicAdd(rs + sg, rp);
  }
}

// ---------------- PV GEMM (R8-verbatim): triple-buffer 128x128xBK=32 ------------------
__global__ __launch_bounds__(256, 2) void gemm_pv(
    const bf16* __restrict__ E, const bf16* __restrict__ H1T,
    const float* __restrict__ rowsum, float* __restrict__ out) {
  extern __shared__ char smem[];
  const int pid = blockIdx.x;
  const int b = pid & 7;
  const int r_ = pid >> 3;
  const int nt = r_ & 3;
  const int mb = r_ >> 2;
  const int mt = (mb < 8) ? 2 * mb : 31 - 2 * mb;
  const int m0 = mt * 128, n0 = nt * 128;
  const int NT = (mt + 1) * 4;
  const bf16* Ab = E + (size_t)b * S_DIM * S_DIM + (size_t)m0 * S_DIM;
  const bf16* Bb = H1T + (size_t)b * D_DIM * S_DIM + (size_t)n0 * S_DIM;
  const float* rs = rowsum + b * S_DIM;
  float* Cb = out + (size_t)b * S_DIM * D_DIM;

  const int tid = threadIdx.x;
  const int w = tid >> 6, L = tid & 63;
  const int l15 = L & 15, lhi = L >> 4;
  const int wr = w >> 1, wc = w & 1;

  const int srow = tid >> 2;
  const int sslot = ((tid & 3) ^ ((tid >> 3) & 3)) * 8;
  const bf16* pA[2];
  const bf16* pB[2];
#pragma unroll
  for (int ld = 0; ld < 2; ld++) {
    pA[ld] = Ab + (size_t)(ld * 64 + srow) * S_DIM + sslot;
    pB[ld] = Bb + (size_t)(ld * 64 + srow) * S_DIM + sslot;
  }

  char* A0 = smem;          char* A1 = smem + 8192;   char* A2 = smem + 16384;
  char* B0 = smem + 24576;  char* B1 = smem + 32768;  char* B2 = smem + 40960;

  auto stage = [&](int t2, char* dA, char* dB) {
#pragma unroll
    for (int ld = 0; ld < 2; ld++)
      load_lds16(pA[ld] + t2 * 32, dA + ld * 4096 + w * 1024);
#pragma unroll
    for (int ld = 0; ld < 2; ld++)
      load_lds16(pB[ld] + t2 * 32, dB + ld * 4096 + w * 1024);
  };

  const int xo = (lhi ^ ((l15 >> 1) & 3)) << 4;
  int offA[4], offB[4];
#pragma unroll
  for (int m = 0; m < 4; m++) offA[m] = (wr * 64 + m * 16 + l15) * 64 + xo;
#pragma unroll
  for (int n = 0; n < 4; n++) offB[n] = (wc * 64 + n * 16 + l15) * 64 + xo;

  f32x4 acc[4][4];
#pragma unroll
  for (int m = 0; m < 4; m++)
#pragma unroll
    for (int n = 0; n < 4; n++) acc[m][n] = (f32x4){0, 0, 0, 0};

  stage(0, A0, B0);
  stage(1, A1, B1);

#pragma unroll 1
  for (int t = 0; t < NT; ++t) {
    if (t < NT - 1) asm volatile("s_waitcnt vmcnt(4)" ::: "memory");
    else            asm volatile("s_waitcnt vmcnt(0)" ::: "memory");
    __builtin_amdgcn_s_barrier();
    asm volatile("" ::: "memory");
    if (t + 2 < NT) stage(t + 2, A2, B2);

    bf16x8 af[4], bfv[4];
#pragma unroll
    for (int m = 0; m < 4; m++) af[m] = *(const bf16x8*)(A0 + offA[m]);
#pragma unroll
    for (int n = 0; n < 4; n++) bfv[n] = *(const bf16x8*)(B0 + offB[n]);
    __builtin_amdgcn_s_setprio(1);
#pragma unroll
    for (int m = 0; m < 4; m++)
#pragma unroll
      for (int n = 0; n < 4; n++)
        acc[m][n] = __builtin_amdgcn_mfma_f32_16x16x32_bf16(bfv[n], af[m], acc[m][n], 0, 0, 0);
    __builtin_amdgcn_s_setprio(0);

    char* tA = A0; A0 = A1; A1 = A2; A2 = tA;
    char* tB = B0; B0 = B1; B1 = B2; B2 = tB;
  }

#pragma unroll
  for (int m = 0; m < 4; m++) {
    int sg = m0 + wr * 64 + m * 16 + l15;
    float inv = 1.0f / rs[sg];
#pragma unroll
    for (int n = 0; n < 4; n++) {
      int gcol = n0 + wc * 64 + n * 16 + lhi * 4;
      float4 o;
      o.x = acc[m][n][0] * inv;
      o.y = acc[m][n][1] * inv;
      o.z = acc[m][n][2] * inv;
      o.w = acc[m][n][3] * inv;
      *(float4*)(Cb + (size_t)sg * D_DIM + gcol) = o;
    }
  }
}

extern "C" void kernel_launch(void* const* d_in, const int* in_sizes, int n_in,
                              void* d_out, int out_size, void* d_ws, size_t ws_size,
                              hipStream_t stream) {
  const float* x1 = (const float*)d_in[0];
  const float* x2 = (const float*)d_in[1];
  const float* km = (const float*)d_in[2];
  float* out = (float*)d_out;
  char* ws = (char*)d_ws;
  // ws layout (bytes):
  //   [0,64M):   E (8 x 2048 x 2048 bf16) -- overlaps phase-1 temporaries below
  //   [0,8M):    Kbf | [8,24M): x1t | [24,40M): x2t   (dead before E is written)
  //   [64,80M):  h1n  [80,96M): h2n  [96,112M): h1t
  //   [112M,+64K): rowsum (8 x 2048 f32)
  bf16* E    = (bf16*)(ws);
  bf16* Kbf  = (bf16*)(ws);
  bf16* x1t  = (bf16*)(ws + (8ull << 20));
  bf16* h1n  = (bf16*)(ws + (64ull << 20));
  bf16* h2n  = (bf16*)(ws + (80ull << 20));
  bf16* h1t  = (bf16*)(ws + (96ull << 20));
  float* rowsum = (float*)(ws + (112ull << 20));

  convert_k<<<2048, 256, 0, stream>>>(km, Kbf, (S_DIM * S_DIM) / 8);
  tr_f2b64<<<dim3(8, 32, 16), 256, 0, stream>>>(x1, x2, x1t);
  gemm_h<<<256, 512, 131072, stream>>>(Kbf, x1t, h1n);
  tr_b2b64<<<dim3(8, 32, 8), 256, 0, stream>>>(h1n, h1t);
  hipMemsetAsync(rowsum, 0, B_DIM * S_DIM * sizeof(float), stream);
  gemm_score<<<288, 512, 98304, stream>>>(h1n, h2n, E, rowsum);
  gemm_pv<<<512, 256, 49152, stream>>>(E, h1t, rowsum, out);
}

// Round 10
// 174.004 us; speedup vs baseline: 1.0021x; 1.0021x over previous
//
#include <hip/hip_runtime.h>
#include <hip/hip_bf16.h>

#define S_DIM 2048
#define D_DIM 512
#define B_DIM 8
#define SCALE 0.02209708691207961f  // 1/sqrt(2048)

typedef __hip_bfloat16 bf16;
typedef short bf16x8 __attribute__((ext_vector_type(8)));
typedef float f32x4 __attribute__((ext_vector_type(4)));

__device__ __forceinline__ unsigned short f2b(float f) {
  __hip_bfloat16 h = __float2bfloat16(f);
  return __builtin_bit_cast(unsigned short, h);
}
__device__ __forceinline__ float b2f(unsigned short s) {
  return __bfloat162float(__builtin_bit_cast(__hip_bfloat16, s));
}

__device__ __forceinline__ void load_lds16(const void* g, void* l) {
  __builtin_amdgcn_global_load_lds((const __attribute__((address_space(1))) void*)g,
                                   (__attribute__((address_space(3))) void*)l, 16, 0, 0);
}

// ---------------- kernel matrix f32 -> bf16 ----------------
__global__ void convert_k(const float* __restrict__ in, bf16* __restrict__ out, int n8) {
  int i = blockIdx.x * blockDim.x + threadIdx.x;
  if (i >= n8) return;
  const float4* p = (const float4*)in;
  float4 a = p[2 * i], b = p[2 * i + 1];
  bf16x8 r;
  r[0] = f2b(a.x); r[1] = f2b(a.y); r[2] = f2b(a.z); r[3] = f2b(a.w);
  r[4] = f2b(b.x); r[5] = f2b(b.y); r[6] = f2b(b.z); r[7] = f2b(b.w);
  ((bf16x8*)out)[i] = r;
}

// ---------------- transpose x1,x2 (S,D) f32 -> (D,S) bf16, 64x64 tiles ----------------
__global__ void tr_f2b64(const float* __restrict__ x1, const float* __restrict__ x2,
                         bf16* __restrict__ out) {
  __shared__ unsigned short t[64][66];
  const int z = blockIdx.z;
  const float* in = (z < 8 ? x1 : x2) + (size_t)(z & 7) * (S_DIM * D_DIM);
  bf16* ob = out + (size_t)z * (size_t)(D_DIM * S_DIM);
  const int r0 = blockIdx.y * 64;
  const int c0 = blockIdx.x * 64;
  const int tid = threadIdx.x;
  const int lr = tid >> 6, lc = tid & 63;
#pragma unroll
  for (int i = 0; i < 16; i++) {
    int r = i * 4 + lr;
    t[lc][r] = f2b(in[(size_t)(r0 + r) * D_DIM + c0 + lc]);
  }
  __syncthreads();
  const int dl = tid >> 4, tq = tid & 15;
#pragma unroll
  for (int j = 0; j < 4; j++) {
    int d = j * 16 + dl;
    const unsigned short* p = &t[d][tq * 4];
    uint2 u;
    u.x = (unsigned)p[0] | ((unsigned)p[1] << 16);
    u.y = (unsigned)p[2] | ((unsigned)p[3] << 16);
    *(uint2*)(ob + (size_t)(c0 + d) * S_DIM + r0 + tq * 4) = u;
  }
}

// ---------------- transpose h1n (S,D) bf16 -> (D,S) bf16, 64x64 tiles ----------------
__global__ void tr_b2b64(const bf16* __restrict__ in, bf16* __restrict__ out) {
  __shared__ unsigned short t[64][66];
  const int z = blockIdx.z;
  const bf16* ib = in + (size_t)z * (S_DIM * D_DIM);
  bf16* ob = out + (size_t)z * (S_DIM * D_DIM);
  const int r0 = blockIdx.y * 64;
  const int c0 = blockIdx.x * 64;
  const int tid = threadIdx.x;
  const int lr = tid >> 5, cp = tid & 31;
#pragma unroll
  for (int i = 0; i < 8; i++) {
    int r = i * 8 + lr;
    unsigned v = *(const unsigned*)(ib + (size_t)(r0 + r) * D_DIM + c0 + cp * 2);
    t[cp * 2][r] = (unsigned short)(v & 0xffff);
    t[cp * 2 + 1][r] = (unsigned short)(v >> 16);
  }
  __syncthreads();
  const int dl = tid >> 4, tq = tid & 15;
#pragma unroll
  for (int j = 0; j < 4; j++) {
    int d = j * 16 + dl;
    const unsigned short* p = &t[d][tq * 4];
    uint2 u;
    u.x = (unsigned)p[0] | ((unsigned)p[1] << 16);
    u.y = (unsigned)p[2] | ((unsigned)p[3] << 16);
    *(uint2*)(ob + (size_t)(c0 + d) * S_DIM + r0 + tq * 4) = u;
  }
}

// ---------------- h-GEMM (R4-verbatim, 73.4us proven): 256x256xBK=32, triple-buffer ----
__global__ __launch_bounds__(512, 2) void gemm_h(
    const bf16* __restrict__ A, const bf16* __restrict__ X, bf16* __restrict__ H) {
  extern __shared__ char smem[];
  const int pid = blockIdx.x;
  const int mt = pid & 7;              // XCD-pinned A panel
  const int r_ = pid >> 3;
  const int ntile = r_ & 1;
  const int item = r_ >> 1;            // 0..15
  const int m0 = mt * 256, n0 = ntile * 256;
  const bf16* Xi = X + (size_t)item * (D_DIM * S_DIM);
  bf16* Hi = H + (size_t)item * (S_DIM * D_DIM);

  const int tid = threadIdx.x;
  const int w = tid >> 6, L = tid & 63;
  const int l15 = L & 15, lhi = L >> 4;
  const int wr = w >> 2, wn = w & 3;

  const int srow = tid >> 2;
  const int sslot = ((tid & 3) ^ ((tid >> 3) & 3)) * 8;
  const bf16* pA[2];
  const bf16* pB[2];
#pragma unroll
  for (int ld = 0; ld < 2; ld++) {
    pA[ld] = A + (size_t)(m0 + ld * 128 + srow) * 2048 + sslot;
    pB[ld] = Xi + (size_t)(n0 + ld * 128 + srow) * 2048 + sslot;
  }

  char* A0 = smem;          char* A1 = smem + 16384;  char* A2 = smem + 32768;
  char* B0 = smem + 49152;  char* B1 = smem + 65536;  char* B2 = smem + 81920;

  auto stage = [&](int t2, char* dA, char* dB) {
#pragma unroll
    for (int ld = 0; ld < 2; ld++)
      load_lds16(pA[ld] + t2 * 32, dA + ld * 8192 + w * 1024);
#pragma unroll
    for (int ld = 0; ld < 2; ld++)
      load_lds16(pB[ld] + t2 * 32, dB + ld * 8192 + w * 1024);
  };

  const int xo = (lhi ^ ((l15 >> 1) & 3)) << 4;
  int offA[8], offB[4];
#pragma unroll
  for (int m = 0; m < 8; m++) offA[m] = (wr * 128 + m * 16 + l15) * 64 + xo;
#pragma unroll
  for (int n = 0; n < 4; n++) offB[n] = (wn * 64 + n * 16 + l15) * 64 + xo;

  f32x4 acc[8][4];
#pragma unroll
  for (int m = 0; m < 8; m++)
#pragma unroll
    for (int n = 0; n < 4; n++) acc[m][n] = (f32x4){0, 0, 0, 0};

  stage(0, A0, B0);
  stage(1, A1, B1);

#pragma unroll 1
  for (int t = 0; t < 64; ++t) {
    if (t < 63) asm volatile("s_waitcnt vmcnt(4)" ::: "memory");
    else        asm volatile("s_waitcnt vmcnt(0)" ::: "memory");
    __builtin_amdgcn_s_barrier();
    asm volatile("" ::: "memory");
    if (t < 62) stage(t + 2, A2, B2);

    bf16x8 af[8], bfv[4];
#pragma unroll
    for (int m = 0; m < 8; m++) af[m] = *(const bf16x8*)(A0 + offA[m]);
#pragma unroll
    for (int n = 0; n < 4; n++) bfv[n] = *(const bf16x8*)(B0 + offB[n]);
    __builtin_amdgcn_s_setprio(1);
#pragma unroll
    for (int m = 0; m < 8; m++)
#pragma unroll
      for (int n = 0; n < 4; n++)
        acc[m][n] = __builtin_amdgcn_mfma_f32_16x16x32_bf16(bfv[n], af[m], acc[m][n], 0, 0, 0);
    __builtin_amdgcn_s_setprio(0);

    char* tA = A0; A0 = A1; A1 = A2; A2 = tA;
    char* tB = B0; B0 = B1; B1 = B2; B2 = tB;
  }

#pragma unroll
  for (int m = 0; m < 8; m++) {
    int grow = m0 + wr * 128 + m * 16 + l15;
#pragma unroll
    for (int n = 0; n < 4; n++) {
      int gcol = n0 + wn * 64 + n * 16 + lhi * 4;
      uint2 u;
      u.x = ((unsigned)f2b(acc[m][n][1]) << 16) | f2b(acc[m][n][0]);
      u.y = ((unsigned)f2b(acc[m][n][3]) << 16) | f2b(acc[m][n][2]);
      *(uint2*)(Hi + (size_t)grow * D_DIM + gcol) = u;
    }
  }
}

// ---------------- score GEMM v2: double-buffered 64KB -> 2 blocks/CU, 288 resident ----
// E = exp(SCALE*h1 h2^T) lower-tri 256 tiles. R6-proven sync: one __syncthreads per step
// (drains vm+lgkm then barriers), stage(t+1) after the barrier into buf (t+1)&1=(t-1)&1,
// whose tile-(t-1) reads were all consumed by MFMAs before any wave passed the barrier.
__global__ __launch_bounds__(512, 2) void gemm_score(
    const bf16* __restrict__ H1, const bf16* __restrict__ H2,
    bf16* __restrict__ E, float* __restrict__ rowsum) {
  extern __shared__ char smem[];
  const int pid = blockIdx.x;
  const int b = pid & 7;           // batch pinned to XCD
  const int tri = pid >> 3;        // 0..35
  int mt = (int)((sqrtf(8.0f * (float)tri + 1.0f) - 1.0f) * 0.5f);
  while ((mt + 1) * (mt + 2) / 2 <= tri) mt++;
  while (mt * (mt + 1) / 2 > tri) mt--;
  const int nt = tri - mt * (mt + 1) / 2;
  const int m0 = mt * 256, n0 = nt * 256;
  const bool diag = (mt == nt);
  const bf16* Ab = H1 + (size_t)b * S_DIM * D_DIM;
  const bf16* Bb = H2 + (size_t)b * S_DIM * D_DIM;
  bf16* Eb = E + (size_t)b * S_DIM * S_DIM;
  float* rs = rowsum + b * S_DIM;

  const int tid = threadIdx.x;
  const int w = tid >> 6, L = tid & 63;
  const int l15 = L & 15, lhi = L >> 4;
  const int wr = w >> 2, wn = w & 3;

  const int srow = tid >> 2;
  const int sslot = ((tid & 3) ^ ((tid >> 3) & 3)) * 8;
  const bf16* pA[2];
  const bf16* pB[2];
#pragma unroll
  for (int ld = 0; ld < 2; ld++) {
    pA[ld] = Ab + (size_t)(m0 + ld * 128 + srow) * D_DIM + sslot;
    pB[ld] = Bb + (size_t)(n0 + ld * 128 + srow) * D_DIM + sslot;
  }

  // LDS 64KB: A bufs 2x16KB @0; B bufs 2x16KB @32KB
  auto stage = [&](int t) {
    char* dA = smem + (t & 1) * 16384;
    char* dB = smem + 32768 + (t & 1) * 16384;
#pragma unroll
    for (int ld = 0; ld < 2; ld++)
      load_lds16(pA[ld] + t * 32, dA + ld * 8192 + w * 1024);
#pragma unroll
    for (int ld = 0; ld < 2; ld++)
      load_lds16(pB[ld] + t * 32, dB + ld * 8192 + w * 1024);
  };

  const int xo = (lhi ^ ((l15 >> 1) & 3)) << 4;
  int offA[8], offB[4];
#pragma unroll
  for (int m = 0; m < 8; m++) offA[m] = (wr * 128 + m * 16 + l15) * 64 + xo;
#pragma unroll
  for (int n = 0; n < 4; n++) offB[n] = (wn * 64 + n * 16 + l15) * 64 + xo;

  f32x4 acc[8][4];
#pragma unroll
  for (int m = 0; m < 8; m++)
#pragma unroll
    for (int n = 0; n < 4; n++) acc[m][n] = (f32x4){0, 0, 0, 0};

  stage(0);
#pragma unroll 2
  for (int t = 0; t < 16; ++t) {
    __syncthreads();                   // drains vm+lgkm, then barrier (R6-proven)
    if (t + 1 < 16) stage(t + 1);
    const char* bA = smem + (t & 1) * 16384;
    const char* bB = smem + 32768 + (t & 1) * 16384;
    bf16x8 af[8], bfv[4];
#pragma unroll
    for (int m = 0; m < 8; m++) af[m] = *(const bf16x8*)(bA + offA[m]);
#pragma unroll
    for (int n = 0; n < 4; n++) bfv[n] = *(const bf16x8*)(bB + offB[n]);
    __builtin_amdgcn_s_setprio(1);
#pragma unroll
    for (int m = 0; m < 8; m++)
#pragma unroll
      for (int n = 0; n < 4; n++)
        acc[m][n] = __builtin_amdgcn_mfma_f32_16x16x32_bf16(bfv[n], af[m], acc[m][n], 0, 0, 0);
    __builtin_amdgcn_s_setprio(0);
  }

#pragma unroll
  for (int m = 0; m < 8; m++) {
    int sg = m0 + wr * 128 + m * 16 + l15;
    float rp = 0.0f;
#pragma unroll
    for (int n = 0; n < 4; n++) {
      int tg0 = n0 + wn * 64 + n * 16 + lhi * 4;
      unsigned short e[4];
#pragma unroll
      for (int r = 0; r < 4; r++) {
        float v = (!diag || (tg0 + r) <= sg) ? __expf(acc[m][n][r] * SCALE) : 0.0f;
        e[r] = f2b(v);
        rp += b2f(e[r]);
      }
      uint2 u;
      u.x = ((unsigned)e[1] << 16) | e[0];
      u.y = ((unsigned)e[3] << 16) | e[2];
      *(uint2*)(Eb + (size_t)sg * S_DIM + tg0) = u;
    }
    rp += __shfl_xor(rp, 16);
    rp += __shfl_xor(rp, 32);
    if (lhi == 0) atomicAdd(rs + sg, rp);
  }
}

// ---------------- PV GEMM (R8-verbatim): triple-buffer 128x128xBK=32 ------------------
__global__ __launch_bounds__(256, 2) void gemm_pv(
    const bf16* __restrict__ E, const bf16* __restrict__ H1T,
    const float* __restrict__ rowsum, float* __restrict__ out) {
  extern __shared__ char smem[];
  const int pid = blockIdx.x;
  const int b = pid & 7;
  const int r_ = pid >> 3;
  const int nt = r_ & 3;
  const int mb = r_ >> 2;
  const int mt = (mb < 8) ? 2 * mb : 31 - 2 * mb;
  const int m0 = mt * 128, n0 = nt * 128;
  const int NT = (mt + 1) * 4;
  const bf16* Ab = E + (size_t)b * S_DIM * S_DIM + (size_t)m0 * S_DIM;
  const bf16* Bb = H1T + (size_t)b * D_DIM * S_DIM + (size_t)n0 * S_DIM;
  const float* rs = rowsum + b * S_DIM;
  float* Cb = out + (size_t)b * S_DIM * D_DIM;

  const int tid = threadIdx.x;
  const int w = tid >> 6, L = tid & 63;
  const int l15 = L & 15, lhi = L >> 4;
  const int wr = w >> 1, wc = w & 1;

  const int srow = tid >> 2;
  const int sslot = ((tid & 3) ^ ((tid >> 3) & 3)) * 8;
  const bf16* pA[2];
  const bf16* pB[2];
#pragma unroll
  for (int ld = 0; ld < 2; ld++) {
    pA[ld] = Ab + (size_t)(ld * 64 + srow) * S_DIM + sslot;
    pB[ld] = Bb + (size_t)(ld * 64 + srow) * S_DIM + sslot;
  }

  char* A0 = smem;          char* A1 = smem + 8192;   char* A2 = smem + 16384;
  char* B0 = smem + 24576;  char* B1 = smem + 32768;  char* B2 = smem + 40960;

  auto stage = [&](int t2, char* dA, char* dB) {
#pragma unroll
    for (int ld = 0; ld < 2; ld++)
      load_lds16(pA[ld] + t2 * 32, dA + ld * 4096 + w * 1024);
#pragma unroll
    for (int ld = 0; ld < 2; ld++)
      load_lds16(pB[ld] + t2 * 32, dB + ld * 4096 + w * 1024);
  };

  const int xo = (lhi ^ ((l15 >> 1) & 3)) << 4;
  int offA[4], offB[4];
#pragma unroll
  for (int m = 0; m < 4; m++) offA[m] = (wr * 64 + m * 16 + l15) * 64 + xo;
#pragma unroll
  for (int n = 0; n < 4; n++) offB[n] = (wc * 64 + n * 16 + l15) * 64 + xo;

  f32x4 acc[4][4];
#pragma unroll
  for (int m = 0; m < 4; m++)
#pragma unroll
    for (int n = 0; n < 4; n++) acc[m][n] = (f32x4){0, 0, 0, 0};

  stage(0, A0, B0);
  stage(1, A1, B1);

#pragma unroll 1
  for (int t = 0; t < NT; ++t) {
    if (t < NT - 1) asm volatile("s_waitcnt vmcnt(4)" ::: "memory");
    else            asm volatile("s_waitcnt vmcnt(0)" ::: "memory");
    __builtin_amdgcn_s_barrier();
    asm volatile("" ::: "memory");
    if (t + 2 < NT) stage(t + 2, A2, B2);

    bf16x8 af[4], bfv[4];
#pragma unroll
    for (int m = 0; m < 4; m++) af[m] = *(const bf16x8*)(A0 + offA[m]);
#pragma unroll
    for (int n = 0; n < 4; n++) bfv[n] = *(const bf16x8*)(B0 + offB[n]);
    __builtin_amdgcn_s_setprio(1);
#pragma unroll
    for (int m = 0; m < 4; m++)
#pragma unroll
      for (int n = 0; n < 4; n++)
        acc[m][n] = __builtin_amdgcn_mfma_f32_16x16x32_bf16(bfv[n], af[m], acc[m][n], 0, 0, 0);
    __builtin_amdgcn_s_setprio(0);

    char* tA = A0; A0 = A1; A1 = A2; A2 = tA;
    char* tB = B0; B0 = B1; B1 = B2; B2 = tB;
  }

#pragma unroll
  for (int m = 0; m < 4; m++) {
    int sg = m0 + wr * 64 + m * 16 + l15;
    float inv = 1.0f / rs[sg];
#pragma unroll
    for (int n = 0; n < 4; n++) {
      int gcol = n0 + wc * 64 + n * 16 + lhi * 4;
      float4 o;
      o.x = acc[m][n][0] * inv;
      o.y = acc[m][n][1] * inv;
      o.z = acc[m][n][2] * inv;
      o.w = acc[m][n][3] * inv;
      *(float4*)(Cb + (size_t)sg * D_DIM + gcol) = o;
    }
  }
}

extern "C" void kernel_launch(void* const* d_in, const int* in_sizes, int n_in,
                              void* d_out, int out_size, void* d_ws, size_t ws_size,
                              hipStream_t stream) {
  const float* x1 = (const float*)d_in[0];
  const float* x2 = (const float*)d_in[1];
  const float* km = (const float*)d_in[2];
  float* out = (float*)d_out;
  char* ws = (char*)d_ws;
  // ws layout (bytes):
  //   [0,64M):   E (8 x 2048 x 2048 bf16) -- overlaps phase-1 temporaries below
  //   [0,8M):    Kbf | [8,24M): x1t | [24,40M): x2t   (dead before E is written)
  //   [64,80M):  h1n  [80,96M): h2n  [96,112M): h1t
  //   [112M,+64K): rowsum (8 x 2048 f32)
  bf16* E    = (bf16*)(ws);
  bf16* Kbf  = (bf16*)(ws);
  bf16* x1t  = (bf16*)(ws + (8ull << 20));
  bf16* h1n  = (bf16*)(ws + (64ull << 20));
  bf16* h2n  = (bf16*)(ws + (80ull << 20));
  bf16* h1t  = (bf16*)(ws + (96ull << 20));
  float* rowsum = (float*)(ws + (112ull << 20));

  convert_k<<<2048, 256, 0, stream>>>(km, Kbf, (S_DIM * S_DIM) / 8);
  tr_f2b64<<<dim3(8, 32, 16), 256, 0, stream>>>(x1, x2, x1t);
  gemm_h<<<256, 512, 98304, stream>>>(Kbf, x1t, h1n);
  tr_b2b64<<<dim3(8, 32, 8), 256, 0, stream>>>(h1n, h1t);
  hipMemsetAsync(rowsum, 0, B_DIM * S_DIM * sizeof(float), stream);
  gemm_score<<<288, 512, 65536, stream>>>(h1n, h2n, E, rowsum);
  gemm_pv<<<512, 256, 49152, stream>>>(E, h1t, rowsum, out);
}

// Round 11
// 170.209 us; speedup vs baseline: 1.0244x; 1.0223x over previous
//
#include <hip/hip_runtime.h>
#include <hip/hip_bf16.h>

#define S_DIM 2048
#define D_DIM 512
#define B_DIM 8
#define SCALE 0.02209708691207961f  // 1/sqrt(2048)

typedef __hip_bfloat16 bf16;
typedef short bf16x8 __attribute__((ext_vector_type(8)));
typedef float f32x4 __attribute__((ext_vector_type(4)));

__device__ __forceinline__ unsigned short f2b(float f) {
  __hip_bfloat16 h = __float2bfloat16(f);
  return __builtin_bit_cast(unsigned short, h);
}
__device__ __forceinline__ float b2f(unsigned short s) {
  return __bfloat162float(__builtin_bit_cast(__hip_bfloat16, s));
}

__device__ __forceinline__ void load_lds16(const void* g, void* l) {
  __builtin_amdgcn_global_load_lds((const __attribute__((address_space(1))) void*)g,
                                   (__attribute__((address_space(3))) void*)l, 16, 0, 0);
}

// ---------------- fused prep: x1,x2 transpose+convert | K convert | rowsum zero --------
// grid (8,32,17) x 256 thr.
//  z<16 : 64x64 tile transpose (S,D) f32 -> (D,S) bf16, float4 loads (16B/lane).
//  z==16: K (2048x2048) f32->bf16 (float4x2 loads, bf16x8 stores); first 8 blocks
//         also zero rowsum. Completes before gemm_h/gemm_score by dispatch ordering.
__global__ void prep(const float* __restrict__ x1, const float* __restrict__ x2,
                     const float* __restrict__ km,
                     bf16* __restrict__ xt, bf16* __restrict__ Kbf,
                     float* __restrict__ rowsum) {
  const int z = blockIdx.z;
  const int tid = threadIdx.x;
  if (z == 16) {
    const int bid = blockIdx.y * 8 + blockIdx.x;   // 0..255
    const float4* p = (const float4*)km;
    bf16x8* o = (bf16x8*)Kbf;
#pragma unroll
    for (int it = 0; it < 8; it++) {
      int i = bid * 2048 + it * 256 + tid;         // 256*8*256 = 524288 = 2048^2/8
      float4 a = p[2 * i], b = p[2 * i + 1];
      bf16x8 r;
      r[0] = f2b(a.x); r[1] = f2b(a.y); r[2] = f2b(a.z); r[3] = f2b(a.w);
      r[4] = f2b(b.x); r[5] = f2b(b.y); r[6] = f2b(b.z); r[7] = f2b(b.w);
      o[i] = r;
    }
    if (bid < 8) {
      float4 zf = {0.0f, 0.0f, 0.0f, 0.0f};
      float4* rp = (float4*)(rowsum + bid * 2048);
      rp[tid * 2] = zf;
      rp[tid * 2 + 1] = zf;                        // 8 blk x 256 thr x 8 f32 = 16384
    }
    return;
  }
  __shared__ unsigned short t[64][66];
  const float* in = (z < 8 ? x1 : x2) + (size_t)(z & 7) * (S_DIM * D_DIM);
  bf16* ob = xt + (size_t)z * (size_t)(D_DIM * S_DIM);
  const int r0 = blockIdx.y * 64;   // S
  const int c0 = blockIdx.x * 64;   // D
  const int lr = tid >> 4, lq = tid & 15;
#pragma unroll
  for (int i = 0; i < 4; i++) {
    int r = i * 16 + lr;
    float4 v = *(const float4*)(in + (size_t)(r0 + r) * D_DIM + c0 + lq * 4);
    t[lq * 4 + 0][r] = f2b(v.x);
    t[lq * 4 + 1][r] = f2b(v.y);
    t[lq * 4 + 2][r] = f2b(v.z);
    t[lq * 4 + 3][r] = f2b(v.w);
  }
  __syncthreads();
#pragma unroll
  for (int j = 0; j < 4; j++) {
    int d = j * 16 + lr;
    const unsigned short* p = &t[d][lq * 4];
    uint2 u;
    u.x = (unsigned)p[0] | ((unsigned)p[1] << 16);
    u.y = (unsigned)p[2] | ((unsigned)p[3] << 16);
    *(uint2*)(ob + (size_t)(c0 + d) * S_DIM + r0 + lq * 4) = u;
  }
}

// ---------------- transpose h1n (S,D) bf16 -> (D,S) bf16, 64x64 tiles, 8B/lane loads ---
__global__ void tr_b2b64(const bf16* __restrict__ in, bf16* __restrict__ out) {
  __shared__ unsigned short t[64][66];
  const int z = blockIdx.z;
  const bf16* ib = in + (size_t)z * (S_DIM * D_DIM);
  bf16* ob = out + (size_t)z * (S_DIM * D_DIM);
  const int r0 = blockIdx.y * 64;
  const int c0 = blockIdx.x * 64;
  const int tid = threadIdx.x;
  const int lr = tid >> 4, lq = tid & 15;
#pragma unroll
  for (int i = 0; i < 4; i++) {
    int r = i * 16 + lr;
    uint2 v = *(const uint2*)(ib + (size_t)(r0 + r) * D_DIM + c0 + lq * 4);
    t[lq * 4 + 0][r] = (unsigned short)(v.x & 0xffff);
    t[lq * 4 + 1][r] = (unsigned short)(v.x >> 16);
    t[lq * 4 + 2][r] = (unsigned short)(v.y & 0xffff);
    t[lq * 4 + 3][r] = (unsigned short)(v.y >> 16);
  }
  __syncthreads();
#pragma unroll
  for (int j = 0; j < 4; j++) {
    int d = j * 16 + lr;
    const unsigned short* p = &t[d][lq * 4];
    uint2 u;
    u.x = (unsigned)p[0] | ((unsigned)p[1] << 16);
    u.y = (unsigned)p[2] | ((unsigned)p[3] << 16);
    *(uint2*)(ob + (size_t)(c0 + d) * S_DIM + r0 + lq * 4) = u;
  }
}

// ---------------- h-GEMM (R4-verbatim, 73.4us proven): 256x256xBK=32, triple-buffer ----
__global__ __launch_bounds__(512, 2) void gemm_h(
    const bf16* __restrict__ A, const bf16* __restrict__ X, bf16* __restrict__ H) {
  extern __shared__ char smem[];
  const int pid = blockIdx.x;
  const int mt = pid & 7;              // XCD-pinned A panel
  const int r_ = pid >> 3;
  const int ntile = r_ & 1;
  const int item = r_ >> 1;            // 0..15
  const int m0 = mt * 256, n0 = ntile * 256;
  const bf16* Xi = X + (size_t)item * (D_DIM * S_DIM);
  bf16* Hi = H + (size_t)item * (S_DIM * D_DIM);

  const int tid = threadIdx.x;
  const int w = tid >> 6, L = tid & 63;
  const int l15 = L & 15, lhi = L >> 4;
  const int wr = w >> 2, wn = w & 3;

  const int srow = tid >> 2;
  const int sslot = ((tid & 3) ^ ((tid >> 3) & 3)) * 8;
  const bf16* pA[2];
  const bf16* pB[2];
#pragma unroll
  for (int ld = 0; ld < 2; ld++) {
    pA[ld] = A + (size_t)(m0 + ld * 128 + srow) * 2048 + sslot;
    pB[ld] = Xi + (size_t)(n0 + ld * 128 + srow) * 2048 + sslot;
  }

  char* A0 = smem;          char* A1 = smem + 16384;  char* A2 = smem + 32768;
  char* B0 = smem + 49152;  char* B1 = smem + 65536;  char* B2 = smem + 81920;

  auto stage = [&](int t2, char* dA, char* dB) {
#pragma unroll
    for (int ld = 0; ld < 2; ld++)
      load_lds16(pA[ld] + t2 * 32, dA + ld * 8192 + w * 1024);
#pragma unroll
    for (int ld = 0; ld < 2; ld++)
      load_lds16(pB[ld] + t2 * 32, dB + ld * 8192 + w * 1024);
  };

  const int xo = (lhi ^ ((l15 >> 1) & 3)) << 4;
  int offA[8], offB[4];
#pragma unroll
  for (int m = 0; m < 8; m++) offA[m] = (wr * 128 + m * 16 + l15) * 64 + xo;
#pragma unroll
  for (int n = 0; n < 4; n++) offB[n] = (wn * 64 + n * 16 + l15) * 64 + xo;

  f32x4 acc[8][4];
#pragma unroll
  for (int m = 0; m < 8; m++)
#pragma unroll
    for (int n = 0; n < 4; n++) acc[m][n] = (f32x4){0, 0, 0, 0};

  stage(0, A0, B0);
  stage(1, A1, B1);

#pragma unroll 1
  for (int t = 0; t < 64; ++t) {
    if (t < 63) asm volatile("s_waitcnt vmcnt(4)" ::: "memory");
    else        asm volatile("s_waitcnt vmcnt(0)" ::: "memory");
    __builtin_amdgcn_s_barrier();
    asm volatile("" ::: "memory");
    if (t < 62) stage(t + 2, A2, B2);

    bf16x8 af[8], bfv[4];
#pragma unroll
    for (int m = 0; m < 8; m++) af[m] = *(const bf16x8*)(A0 + offA[m]);
#pragma unroll
    for (int n = 0; n < 4; n++) bfv[n] = *(const bf16x8*)(B0 + offB[n]);
    __builtin_amdgcn_s_setprio(1);
#pragma unroll
    for (int m = 0; m < 8; m++)
#pragma unroll
      for (int n = 0; n < 4; n++)
        acc[m][n] = __builtin_amdgcn_mfma_f32_16x16x32_bf16(bfv[n], af[m], acc[m][n], 0, 0, 0);
    __builtin_amdgcn_s_setprio(0);

    char* tA = A0; A0 = A1; A1 = A2; A2 = tA;
    char* tB = B0; B0 = B1; B1 = B2; B2 = tB;
  }

#pragma unroll
  for (int m = 0; m < 8; m++) {
    int grow = m0 + wr * 128 + m * 16 + l15;
#pragma unroll
    for (int n = 0; n < 4; n++) {
      int gcol = n0 + wn * 64 + n * 16 + lhi * 4;
      uint2 u;
      u.x = ((unsigned)f2b(acc[m][n][1]) << 16) | f2b(acc[m][n][0]);
      u.y = ((unsigned)f2b(acc[m][n][3]) << 16) | f2b(acc[m][n][2]);
      *(uint2*)(Hi + (size_t)grow * D_DIM + gcol) = u;
    }
  }
}

// ---------------- score GEMM (R10-verbatim): double-buffered 64KB, 2 blocks/CU --------
__global__ __launch_bounds__(512, 2) void gemm_score(
    const bf16* __restrict__ H1, const bf16* __restrict__ H2,
    bf16* __restrict__ E, float* __restrict__ rowsum) {
  extern __shared__ char smem[];
  const int pid = blockIdx.x;
  const int b = pid & 7;           // batch pinned to XCD
  const int tri = pid >> 3;        // 0..35
  int mt = (int)((sqrtf(8.0f * (float)tri + 1.0f) - 1.0f) * 0.5f);
  while ((mt + 1) * (mt + 2) / 2 <= tri) mt++;
  while (mt * (mt + 1) / 2 > tri) mt--;
  const int nt = tri - mt * (mt + 1) / 2;
  const int m0 = mt * 256, n0 = nt * 256;
  const bool diag = (mt == nt);
  const bf16* Ab = H1 + (size_t)b * S_DIM * D_DIM;
  const bf16* Bb = H2 + (size_t)b * S_DIM * D_DIM;
  bf16* Eb = E + (size_t)b * S_DIM * S_DIM;
  float* rs = rowsum + b * S_DIM;

  const int tid = threadIdx.x;
  const int w = tid >> 6, L = tid & 63;
  const int l15 = L & 15, lhi = L >> 4;
  const int wr = w >> 2, wn = w & 3;

  const int srow = tid >> 2;
  const int sslot = ((tid & 3) ^ ((tid >> 3) & 3)) * 8;
  const bf16* pA[2];
  const bf16* pB[2];
#pragma unroll
  for (int ld = 0; ld < 2; ld++) {
    pA[ld] = Ab + (size_t)(m0 + ld * 128 + srow) * D_DIM + sslot;
    pB[ld] = Bb + (size_t)(n0 + ld * 128 + srow) * D_DIM + sslot;
  }

  auto stage = [&](int t) {
    char* dA = smem + (t & 1) * 16384;
    char* dB = smem + 32768 + (t & 1) * 16384;
#pragma unroll
    for (int ld = 0; ld < 2; ld++)
      load_lds16(pA[ld] + t * 32, dA + ld * 8192 + w * 1024);
#pragma unroll
    for (int ld = 0; ld < 2; ld++)
      load_lds16(pB[ld] + t * 32, dB + ld * 8192 + w * 1024);
  };

  const int xo = (lhi ^ ((l15 >> 1) & 3)) << 4;
  int offA[8], offB[4];
#pragma unroll
  for (int m = 0; m < 8; m++) offA[m] = (wr * 128 + m * 16 + l15) * 64 + xo;
#pragma unroll
  for (int n = 0; n < 4; n++) offB[n] = (wn * 64 + n * 16 + l15) * 64 + xo;

  f32x4 acc[8][4];
#pragma unroll
  for (int m = 0; m < 8; m++)
#pragma unroll
    for (int n = 0; n < 4; n++) acc[m][n] = (f32x4){0, 0, 0, 0};

  stage(0);
#pragma unroll 2
  for (int t = 0; t < 16; ++t) {
    __syncthreads();
    if (t + 1 < 16) stage(t + 1);
    const char* bA = smem + (t & 1) * 16384;
    const char* bB = smem + 32768 + (t & 1) * 16384;
    bf16x8 af[8], bfv[4];
#pragma unroll
    for (int m = 0; m < 8; m++) af[m] = *(const bf16x8*)(bA + offA[m]);
#pragma unroll
    for (int n = 0; n < 4; n++) bfv[n] = *(const bf16x8*)(bB + offB[n]);
    __builtin_amdgcn_s_setprio(1);
#pragma unroll
    for (int m = 0; m < 8; m++)
#pragma unroll
      for (int n = 0; n < 4; n++)
        acc[m][n] = __builtin_amdgcn_mfma_f32_16x16x32_bf16(bfv[n], af[m], acc[m][n], 0, 0, 0);
    __builtin_amdgcn_s_setprio(0);
  }

#pragma unroll
  for (int m = 0; m < 8; m++) {
    int sg = m0 + wr * 128 + m * 16 + l15;
    float rp = 0.0f;
#pragma unroll
    for (int n = 0; n < 4; n++) {
      int tg0 = n0 + wn * 64 + n * 16 + lhi * 4;
      unsigned short e[4];
#pragma unroll
      for (int r = 0; r < 4; r++) {
        float v = (!diag || (tg0 + r) <= sg) ? __expf(acc[m][n][r] * SCALE) : 0.0f;
        e[r] = f2b(v);
        rp += b2f(e[r]);
      }
      uint2 u;
      u.x = ((unsigned)e[1] << 16) | e[0];
      u.y = ((unsigned)e[3] << 16) | e[2];
      *(uint2*)(Eb + (size_t)sg * S_DIM + tg0) = u;
    }
    rp += __shfl_xor(rp, 16);
    rp += __shfl_xor(rp, 32);
    if (lhi == 0) atomicAdd(rs + sg, rp);
  }
}

// ---------------- PV GEMM (R8-verbatim): triple-buffer 128x128xBK=32 ------------------
__global__ __launch_bounds__(256, 2) void gemm_pv(
    const bf16* __restrict__ E, const bf16* __restrict__ H1T,
    const float* __restrict__ rowsum, float* __restrict__ out) {
  extern __shared__ char smem[];
  const int pid = blockIdx.x;
  const int b = pid & 7;
  const int r_ = pid >> 3;
  const int nt = r_ & 3;
  const int mb = r_ >> 2;
  const int mt = (mb < 8) ? 2 * mb : 31 - 2 * mb;
  const int m0 = mt * 128, n0 = nt * 128;
  const int NT = (mt + 1) * 4;
  const bf16* Ab = E + (size_t)b * S_DIM * S_DIM + (size_t)m0 * S_DIM;
  const bf16* Bb = H1T + (size_t)b * D_DIM * S_DIM + (size_t)n0 * S_DIM;
  const float* rs = rowsum + b * S_DIM;
  float* Cb = out + (size_t)b * S_DIM * D_DIM;

  const int tid = threadIdx.x;
  const int w = tid >> 6, L = tid & 63;
  const int l15 = L & 15, lhi = L >> 4;
  const int wr = w >> 1, wc = w & 1;

  const int srow = tid >> 2;
  const int sslot = ((tid & 3) ^ ((tid >> 3) & 3)) * 8;
  const bf16* pA[2];
  const bf16* pB[2];
#pragma unroll
  for (int ld = 0; ld < 2; ld++) {
    pA[ld] = Ab + (size_t)(ld * 64 + srow) * S_DIM + sslot;
    pB[ld] = Bb + (size_t)(ld * 64 + srow) * S_DIM + sslot;
  }

  char* A0 = smem;          char* A1 = smem + 8192;   char* A2 = smem + 16384;
  char* B0 = smem + 24576;  char* B1 = smem + 32768;  char* B2 = smem + 40960;

  auto stage = [&](int t2, char* dA, char* dB) {
#pragma unroll
    for (int ld = 0; ld < 2; ld++)
      load_lds16(pA[ld] + t2 * 32, dA + ld * 4096 + w * 1024);
#pragma unroll
    for (int ld = 0; ld < 2; ld++)
      load_lds16(pB[ld] + t2 * 32, dB + ld * 4096 + w * 1024);
  };

  const int xo = (lhi ^ ((l15 >> 1) & 3)) << 4;
  int offA[4], offB[4];
#pragma unroll
  for (int m = 0; m < 4; m++) offA[m] = (wr * 64 + m * 16 + l15) * 64 + xo;
#pragma unroll
  for (int n = 0; n < 4; n++) offB[n] = (wc * 64 + n * 16 + l15) * 64 + xo;

  f32x4 acc[4][4];
#pragma unroll
  for (int m = 0; m < 4; m++)
#pragma unroll
    for (int n = 0; n < 4; n++) acc[m][n] = (f32x4){0, 0, 0, 0};

  stage(0, A0, B0);
  stage(1, A1, B1);

#pragma unroll 1
  for (int t = 0; t < NT; ++t) {
    if (t < NT - 1) asm volatile("s_waitcnt vmcnt(4)" ::: "memory");
    else            asm volatile("s_waitcnt vmcnt(0)" ::: "memory");
    __builtin_amdgcn_s_barrier();
    asm volatile("" ::: "memory");
    if (t + 2 < NT) stage(t + 2, A2, B2);

    bf16x8 af[4], bfv[4];
#pragma unroll
    for (int m = 0; m < 4; m++) af[m] = *(const bf16x8*)(A0 + offA[m]);
#pragma unroll
    for (int n = 0; n < 4; n++) bfv[n] = *(const bf16x8*)(B0 + offB[n]);
    __builtin_amdgcn_s_setprio(1);
#pragma unroll
    for (int m = 0; m < 4; m++)
#pragma unroll
      for (int n = 0; n < 4; n++)
        acc[m][n] = __builtin_amdgcn_mfma_f32_16x16x32_bf16(bfv[n], af[m], acc[m][n], 0, 0, 0);
    __builtin_amdgcn_s_setprio(0);

    char* tA = A0; A0 = A1; A1 = A2; A2 = tA;
    char* tB = B0; B0 = B1; B1 = B2; B2 = tB;
  }

#pragma unroll
  for (int m = 0; m < 4; m++) {
    int sg = m0 + wr * 64 + m * 16 + l15;
    float inv = 1.0f / rs[sg];
#pragma unroll
    for (int n = 0; n < 4; n++) {
      int gcol = n0 + wc * 64 + n * 16 + lhi * 4;
      float4 o;
      o.x = acc[m][n][0] * inv;
      o.y = acc[m][n][1] * inv;
      o.z = acc[m][n][2] * inv;
      o.w = acc[m][n][3] * inv;
      *(float4*)(Cb + (size_t)sg * D_DIM + gcol) = o;
    }
  }
}

extern "C" void kernel_launch(void* const* d_in, const int* in_sizes, int n_in,
                              void* d_out, int out_size, void* d_ws, size_t ws_size,
                              hipStream_t stream) {
  const float* x1 = (const float*)d_in[0];
  const float* x2 = (const float*)d_in[1];
  const float* km = (const float*)d_in[2];
  float* out = (float*)d_out;
  char* ws = (char*)d_ws;
  // ws layout (bytes):
  //   [0,64M):   E (8 x 2048 x 2048 bf16) -- overlaps phase-1 temporaries below
  //   [0,8M):    Kbf | [8,24M): x1t | [24,40M): x2t   (dead before E is written)
  //   [64,80M):  h1n  [80,96M): h2n  [96,112M): h1t
  //   [112M,+64K): rowsum (8 x 2048 f32)
  bf16* E    = (bf16*)(ws);
  bf16* Kbf  = (bf16*)(ws);
  bf16* x1t  = (bf16*)(ws + (8ull << 20));
  bf16* h1n  = (bf16*)(ws + (64ull << 20));
  bf16* h2n  = (bf16*)(ws + (80ull << 20));
  bf16* h1t  = (bf16*)(ws + (96ull << 20));
  float* rowsum = (float*)(ws + (112ull << 20));

  prep<<<dim3(8, 32, 17), 256, 0, stream>>>(x1, x2, km, x1t, Kbf, rowsum);
  gemm_h<<<256, 512, 98304, stream>>>(Kbf, x1t, h1n);
  tr_b2b64<<<dim3(8, 32, 8), 256, 0, stream>>>(h1n, h1t);
  gemm_score<<<288, 512, 65536, stream>>>(h1n, h2n, E, rowsum);
  gemm_pv<<<512, 256, 49152, stream>>>(E, h1t, rowsum, out);
}

// Round 12
// 166.042 us; speedup vs baseline: 1.0501x; 1.0251x over previous
//
#include <hip/hip_runtime.h>
#include <hip/hip_bf16.h>

#define S_DIM 2048
#define D_DIM 512
#define B_DIM 8
#define SCALE 0.02209708691207961f  // 1/sqrt(2048)

typedef __hip_bfloat16 bf16;
typedef short bf16x8 __attribute__((ext_vector_type(8)));
typedef float f32x4 __attribute__((ext_vector_type(4)));

__device__ __forceinline__ unsigned short f2b(float f) {
  __hip_bfloat16 h = __float2bfloat16(f);
  return __builtin_bit_cast(unsigned short, h);
}
__device__ __forceinline__ float b2f(unsigned short s) {
  return __bfloat162float(__builtin_bit_cast(__hip_bfloat16, s));
}

__device__ __forceinline__ void load_lds16(const void* g, void* l) {
  __builtin_amdgcn_global_load_lds((const __attribute__((address_space(1))) void*)g,
                                   (__attribute__((address_space(3))) void*)l, 16, 0, 0);
}

// ---------------- fused prep: x1,x2 transpose+convert | K convert | rowsum zero --------
__global__ void prep(const float* __restrict__ x1, const float* __restrict__ x2,
                     const float* __restrict__ km,
                     bf16* __restrict__ xt, bf16* __restrict__ Kbf,
                     float* __restrict__ rowsum) {
  const int z = blockIdx.z;
  const int tid = threadIdx.x;
  if (z == 16) {
    const int bid = blockIdx.y * 8 + blockIdx.x;   // 0..255
    const float4* p = (const float4*)km;
    bf16x8* o = (bf16x8*)Kbf;
#pragma unroll
    for (int it = 0; it < 8; it++) {
      int i = bid * 2048 + it * 256 + tid;
      float4 a = p[2 * i], b = p[2 * i + 1];
      bf16x8 r;
      r[0] = f2b(a.x); r[1] = f2b(a.y); r[2] = f2b(a.z); r[3] = f2b(a.w);
      r[4] = f2b(b.x); r[5] = f2b(b.y); r[6] = f2b(b.z); r[7] = f2b(b.w);
      o[i] = r;
    }
    if (bid < 8) {
      float4 zf = {0.0f, 0.0f, 0.0f, 0.0f};
      float4* rp = (float4*)(rowsum + bid * 2048);
      rp[tid * 2] = zf;
      rp[tid * 2 + 1] = zf;
    }
    return;
  }
  __shared__ unsigned short t[64][66];
  const float* in = (z < 8 ? x1 : x2) + (size_t)(z & 7) * (S_DIM * D_DIM);
  bf16* ob = xt + (size_t)z * (size_t)(D_DIM * S_DIM);
  const int r0 = blockIdx.y * 64;   // S
  const int c0 = blockIdx.x * 64;   // D
  const int lr = tid >> 4, lq = tid & 15;
#pragma unroll
  for (int i = 0; i < 4; i++) {
    int r = i * 16 + lr;
    float4 v = *(const float4*)(in + (size_t)(r0 + r) * D_DIM + c0 + lq * 4);
    t[lq * 4 + 0][r] = f2b(v.x);
    t[lq * 4 + 1][r] = f2b(v.y);
    t[lq * 4 + 2][r] = f2b(v.z);
    t[lq * 4 + 3][r] = f2b(v.w);
  }
  __syncthreads();
#pragma unroll
  for (int j = 0; j < 4; j++) {
    int d = j * 16 + lr;
    const unsigned short* p = &t[d][lq * 4];
    uint2 u;
    u.x = (unsigned)p[0] | ((unsigned)p[1] << 16);
    u.y = (unsigned)p[2] | ((unsigned)p[3] << 16);
    *(uint2*)(ob + (size_t)(c0 + d) * S_DIM + r0 + lq * 4) = u;
  }
}

// ---------------- h-GEMM (R4-verbatim, 73.4us proven): 256x256xBK=32, triple-buffer ----
__global__ __launch_bounds__(512, 2) void gemm_h(
    const bf16* __restrict__ A, const bf16* __restrict__ X, bf16* __restrict__ H) {
  extern __shared__ char smem[];
  const int pid = blockIdx.x;
  const int mt = pid & 7;              // XCD-pinned A panel
  const int r_ = pid >> 3;
  const int ntile = r_ & 1;
  const int item = r_ >> 1;            // 0..15
  const int m0 = mt * 256, n0 = ntile * 256;
  const bf16* Xi = X + (size_t)item * (D_DIM * S_DIM);
  bf16* Hi = H + (size_t)item * (S_DIM * D_DIM);

  const int tid = threadIdx.x;
  const int w = tid >> 6, L = tid & 63;
  const int l15 = L & 15, lhi = L >> 4;
  const int wr = w >> 2, wn = w & 3;

  const int srow = tid >> 2;
  const int sslot = ((tid & 3) ^ ((tid >> 3) & 3)) * 8;
  const bf16* pA[2];
  const bf16* pB[2];
#pragma unroll
  for (int ld = 0; ld < 2; ld++) {
    pA[ld] = A + (size_t)(m0 + ld * 128 + srow) * 2048 + sslot;
    pB[ld] = Xi + (size_t)(n0 + ld * 128 + srow) * 2048 + sslot;
  }

  char* A0 = smem;          char* A1 = smem + 16384;  char* A2 = smem + 32768;
  char* B0 = smem + 49152;  char* B1 = smem + 65536;  char* B2 = smem + 81920;

  auto stage = [&](int t2, char* dA, char* dB) {
#pragma unroll
    for (int ld = 0; ld < 2; ld++)
      load_lds16(pA[ld] + t2 * 32, dA + ld * 8192 + w * 1024);
#pragma unroll
    for (int ld = 0; ld < 2; ld++)
      load_lds16(pB[ld] + t2 * 32, dB + ld * 8192 + w * 1024);
  };

  const int xo = (lhi ^ ((l15 >> 1) & 3)) << 4;
  int offA[8], offB[4];
#pragma unroll
  for (int m = 0; m < 8; m++) offA[m] = (wr * 128 + m * 16 + l15) * 64 + xo;
#pragma unroll
  for (int n = 0; n < 4; n++) offB[n] = (wn * 64 + n * 16 + l15) * 64 + xo;

  f32x4 acc[8][4];
#pragma unroll
  for (int m = 0; m < 8; m++)
#pragma unroll
    for (int n = 0; n < 4; n++) acc[m][n] = (f32x4){0, 0, 0, 0};

  stage(0, A0, B0);
  stage(1, A1, B1);

#pragma unroll 1
  for (int t = 0; t < 64; ++t) {
    if (t < 63) asm volatile("s_waitcnt vmcnt(4)" ::: "memory");
    else        asm volatile("s_waitcnt vmcnt(0)" ::: "memory");
    __builtin_amdgcn_s_barrier();
    asm volatile("" ::: "memory");
    if (t < 62) stage(t + 2, A2, B2);

    bf16x8 af[8], bfv[4];
#pragma unroll
    for (int m = 0; m < 8; m++) af[m] = *(const bf16x8*)(A0 + offA[m]);
#pragma unroll
    for (int n = 0; n < 4; n++) bfv[n] = *(const bf16x8*)(B0 + offB[n]);
    __builtin_amdgcn_s_setprio(1);
#pragma unroll
    for (int m = 0; m < 8; m++)
#pragma unroll
      for (int n = 0; n < 4; n++)
        acc[m][n] = __builtin_amdgcn_mfma_f32_16x16x32_bf16(bfv[n], af[m], acc[m][n], 0, 0, 0);
    __builtin_amdgcn_s_setprio(0);

    char* tA = A0; A0 = A1; A1 = A2; A2 = tA;
    char* tB = B0; B0 = B1; B1 = B2; B2 = tB;
  }

#pragma unroll
  for (int m = 0; m < 8; m++) {
    int grow = m0 + wr * 128 + m * 16 + l15;
#pragma unroll
    for (int n = 0; n < 4; n++) {
      int gcol = n0 + wn * 64 + n * 16 + lhi * 4;
      uint2 u;
      u.x = ((unsigned)f2b(acc[m][n][1]) << 16) | f2b(acc[m][n][0]);
      u.y = ((unsigned)f2b(acc[m][n][3]) << 16) | f2b(acc[m][n][2]);
      *(uint2*)(Hi + (size_t)grow * D_DIM + gcol) = u;
    }
  }
}

// ---------------- score GEMM + fused h1n->h1t transpose ------------------------------
// pid < 288: R10-verbatim double-buffered score (E = exp(SCALE*h1 h2^T), lower-tri).
// pid >= 288 (256 blocks): transpose h1n (B,S,D) -> h1t (B,D,S); independent of score,
// fills the CUs score leaves idle. Each 256-thread half does 4 64x64 tiles.
__global__ __launch_bounds__(512, 2) void gemm_score(
    const bf16* __restrict__ H1, const bf16* __restrict__ H2,
    bf16* __restrict__ E, float* __restrict__ rowsum, bf16* __restrict__ H1T) {
  extern __shared__ char smem[];
  const int pid = blockIdx.x;
  const int tid = threadIdx.x;

  if (pid >= 288) {
    // ---- transpose path ----
    const int tb = pid - 288;                 // 0..255
    const int half = tid >> 8;                // 0/1
    const int t5 = tid & 255;
    unsigned short (*tl)[66] = (unsigned short (*)[66])(smem + half * 8448);
    const int lr = t5 >> 4, lq = t5 & 15;
#pragma unroll 1
    for (int i = 0; i < 4; i++) {
      const int tile = tb * 8 + half * 4 + i;   // 0..2047
      const int z = tile >> 8;
      const int rem = tile & 255;
      const int r0 = (rem >> 3) * 64;           // S
      const int c0 = (rem & 7) * 64;            // D
      const bf16* ib = H1 + (size_t)z * (S_DIM * D_DIM);
      bf16* ob = H1T + (size_t)z * (S_DIM * D_DIM);
#pragma unroll
      for (int j = 0; j < 4; j++) {
        int r = j * 16 + lr;
        uint2 v = *(const uint2*)(ib + (size_t)(r0 + r) * D_DIM + c0 + lq * 4);
        tl[lq * 4 + 0][r] = (unsigned short)(v.x & 0xffff);
        tl[lq * 4 + 1][r] = (unsigned short)(v.x >> 16);
        tl[lq * 4 + 2][r] = (unsigned short)(v.y & 0xffff);
        tl[lq * 4 + 3][r] = (unsigned short)(v.y >> 16);
      }
      __syncthreads();
#pragma unroll
      for (int j = 0; j < 4; j++) {
        int d = j * 16 + lr;
        const unsigned short* p = &tl[d][lq * 4];
        uint2 u;
        u.x = (unsigned)p[0] | ((unsigned)p[1] << 16);
        u.y = (unsigned)p[2] | ((unsigned)p[3] << 16);
        *(uint2*)(ob + (size_t)(c0 + d) * S_DIM + r0 + lq * 4) = u;
      }
      __syncthreads();
    }
    return;
  }

  // ---- score path (R10-verbatim) ----
  const int b = pid & 7;           // batch pinned to XCD
  const int tri = pid >> 3;        // 0..35
  int mt = (int)((sqrtf(8.0f * (float)tri + 1.0f) - 1.0f) * 0.5f);
  while ((mt + 1) * (mt + 2) / 2 <= tri) mt++;
  while (mt * (mt + 1) / 2 > tri) mt--;
  const int nt = tri - mt * (mt + 1) / 2;
  const int m0 = mt * 256, n0 = nt * 256;
  const bool diag = (mt == nt);
  const bf16* Ab = H1 + (size_t)b * S_DIM * D_DIM;
  const bf16* Bb = H2 + (size_t)b * S_DIM * D_DIM;
  bf16* Eb = E + (size_t)b * S_DIM * S_DIM;
  float* rs = rowsum + b * S_DIM;

  const int w = tid >> 6, L = tid & 63;
  const int l15 = L & 15, lhi = L >> 4;
  const int wr = w >> 2, wn = w & 3;

  const int srow = tid >> 2;
  const int sslot = ((tid & 3) ^ ((tid >> 3) & 3)) * 8;
  const bf16* pA[2];
  const bf16* pB[2];
#pragma unroll
  for (int ld = 0; ld < 2; ld++) {
    pA[ld] = Ab + (size_t)(m0 + ld * 128 + srow) * D_DIM + sslot;
    pB[ld] = Bb + (size_t)(n0 + ld * 128 + srow) * D_DIM + sslot;
  }

  auto stage = [&](int t) {
    char* dA = smem + (t & 1) * 16384;
    char* dB = smem + 32768 + (t & 1) * 16384;
#pragma unroll
    for (int ld = 0; ld < 2; ld++)
      load_lds16(pA[ld] + t * 32, dA + ld * 8192 + w * 1024);
#pragma unroll
    for (int ld = 0; ld < 2; ld++)
      load_lds16(pB[ld] + t * 32, dB + ld * 8192 + w * 1024);
  };

  const int xo = (lhi ^ ((l15 >> 1) & 3)) << 4;
  int offA[8], offB[4];
#pragma unroll
  for (int m = 0; m < 8; m++) offA[m] = (wr * 128 + m * 16 + l15) * 64 + xo;
#pragma unroll
  for (int n = 0; n < 4; n++) offB[n] = (wn * 64 + n * 16 + l15) * 64 + xo;

  f32x4 acc[8][4];
#pragma unroll
  for (int m = 0; m < 8; m++)
#pragma unroll
    for (int n = 0; n < 4; n++) acc[m][n] = (f32x4){0, 0, 0, 0};

  stage(0);
#pragma unroll 2
  for (int t = 0; t < 16; ++t) {
    __syncthreads();
    if (t + 1 < 16) stage(t + 1);
    const char* bA = smem + (t & 1) * 16384;
    const char* bB = smem + 32768 + (t & 1) * 16384;
    bf16x8 af[8], bfv[4];
#pragma unroll
    for (int m = 0; m < 8; m++) af[m] = *(const bf16x8*)(bA + offA[m]);
#pragma unroll
    for (int n = 0; n < 4; n++) bfv[n] = *(const bf16x8*)(bB + offB[n]);
    __builtin_amdgcn_s_setprio(1);
#pragma unroll
    for (int m = 0; m < 8; m++)
#pragma unroll
      for (int n = 0; n < 4; n++)
        acc[m][n] = __builtin_amdgcn_mfma_f32_16x16x32_bf16(bfv[n], af[m], acc[m][n], 0, 0, 0);
    __builtin_amdgcn_s_setprio(0);
  }

#pragma unroll
  for (int m = 0; m < 8; m++) {
    int sg = m0 + wr * 128 + m * 16 + l15;
    float rp = 0.0f;
#pragma unroll
    for (int n = 0; n < 4; n++) {
      int tg0 = n0 + wn * 64 + n * 16 + lhi * 4;
      unsigned short e[4];
#pragma unroll
      for (int r = 0; r < 4; r++) {
        float v = (!diag || (tg0 + r) <= sg) ? __expf(acc[m][n][r] * SCALE) : 0.0f;
        e[r] = f2b(v);
        rp += b2f(e[r]);
      }
      uint2 u;
      u.x = ((unsigned)e[1] << 16) | e[0];
      u.y = ((unsigned)e[3] << 16) | e[2];
      *(uint2*)(Eb + (size_t)sg * S_DIM + tg0) = u;
    }
    rp += __shfl_xor(rp, 16);
    rp += __shfl_xor(rp, 32);
    if (lhi == 0) atomicAdd(rs + sg, rp);
  }
}

// ---------------- PV GEMM (R8-verbatim): triple-buffer 128x128xBK=32 ------------------
__global__ __launch_bounds__(256, 2) void gemm_pv(
    const bf16* __restrict__ E, const bf16* __restrict__ H1T,
    const float* __restrict__ rowsum, float* __restrict__ out) {
  extern __shared__ char smem[];
  const int pid = blockIdx.x;
  const int b = pid & 7;
  const int r_ = pid >> 3;
  const int nt = r_ & 3;
  const int mb = r_ >> 2;
  const int mt = (mb < 8) ? 2 * mb : 31 - 2 * mb;
  const int m0 = mt * 128, n0 = nt * 128;
  const int NT = (mt + 1) * 4;
  const bf16* Ab = E + (size_t)b * S_DIM * S_DIM + (size_t)m0 * S_DIM;
  const bf16* Bb = H1T + (size_t)b * D_DIM * S_DIM + (size_t)n0 * S_DIM;
  const float* rs = rowsum + b * S_DIM;
  float* Cb = out + (size_t)b * S_DIM * D_DIM;

  const int tid = threadIdx.x;
  const int w = tid >> 6, L = tid & 63;
  const int l15 = L & 15, lhi = L >> 4;
  const int wr = w >> 1, wc = w & 1;

  const int srow = tid >> 2;
  const int sslot = ((tid & 3) ^ ((tid >> 3) & 3)) * 8;
  const bf16* pA[2];
  const bf16* pB[2];
#pragma unroll
  for (int ld = 0; ld < 2; ld++) {
    pA[ld] = Ab + (size_t)(ld * 64 + srow) * S_DIM + sslot;
    pB[ld] = Bb + (size_t)(ld * 64 + srow) * S_DIM + sslot;
  }

  char* A0 = smem;          char* A1 = smem + 8192;   char* A2 = smem + 16384;
  char* B0 = smem + 24576;  char* B1 = smem + 32768;  char* B2 = smem + 40960;

  auto stage = [&](int t2, char* dA, char* dB) {
#pragma unroll
    for (int ld = 0; ld < 2; ld++)
      load_lds16(pA[ld] + t2 * 32, dA + ld * 4096 + w * 1024);
#pragma unroll
    for (int ld = 0; ld < 2; ld++)
      load_lds16(pB[ld] + t2 * 32, dB + ld * 4096 + w * 1024);
  };

  const int xo = (lhi ^ ((l15 >> 1) & 3)) << 4;
  int offA[4], offB[4];
#pragma unroll
  for (int m = 0; m < 4; m++) offA[m] = (wr * 64 + m * 16 + l15) * 64 + xo;
#pragma unroll
  for (int n = 0; n < 4; n++) offB[n] = (wc * 64 + n * 16 + l15) * 64 + xo;

  f32x4 acc[4][4];
#pragma unroll
  for (int m = 0; m < 4; m++)
#pragma unroll
    for (int n = 0; n < 4; n++) acc[m][n] = (f32x4){0, 0, 0, 0};

  stage(0, A0, B0);
  stage(1, A1, B1);

#pragma unroll 1
  for (int t = 0; t < NT; ++t) {
    if (t < NT - 1) asm volatile("s_waitcnt vmcnt(4)" ::: "memory");
    else            asm volatile("s_waitcnt vmcnt(0)" ::: "memory");
    __builtin_amdgcn_s_barrier();
    asm volatile("" ::: "memory");
    if (t + 2 < NT) stage(t + 2, A2, B2);

    bf16x8 af[4], bfv[4];
#pragma unroll
    for (int m = 0; m < 4; m++) af[m] = *(const bf16x8*)(A0 + offA[m]);
#pragma unroll
    for (int n = 0; n < 4; n++) bfv[n] = *(const bf16x8*)(B0 + offB[n]);
    __builtin_amdgcn_s_setprio(1);
#pragma unroll
    for (int m = 0; m < 4; m++)
#pragma unroll
      for (int n = 0; n < 4; n++)
        acc[m][n] = __builtin_amdgcn_mfma_f32_16x16x32_bf16(bfv[n], af[m], acc[m][n], 0, 0, 0);
    __builtin_amdgcn_s_setprio(0);

    char* tA = A0; A0 = A1; A1 = A2; A2 = tA;
    char* tB = B0; B0 = B1; B1 = B2; B2 = tB;
  }

#pragma unroll
  for (int m = 0; m < 4; m++) {
    int sg = m0 + wr * 64 + m * 16 + l15;
    float inv = 1.0f / rs[sg];
#pragma unroll
    for (int n = 0; n < 4; n++) {
      int gcol = n0 + wc * 64 + n * 16 + lhi * 4;
      float4 o;
      o.x = acc[m][n][0] * inv;
      o.y = acc[m][n][1] * inv;
      o.z = acc[m][n][2] * inv;
      o.w = acc[m][n][3] * inv;
      *(float4*)(Cb + (size_t)sg * D_DIM + gcol) = o;
    }
  }
}

extern "C" void kernel_launch(void* const* d_in, const int* in_sizes, int n_in,
                              void* d_out, int out_size, void* d_ws, size_t ws_size,
                              hipStream_t stream) {
  const float* x1 = (const float*)d_in[0];
  const float* x2 = (const float*)d_in[1];
  const float* km = (const float*)d_in[2];
  float* out = (float*)d_out;
  char* ws = (char*)d_ws;
  // ws layout (bytes):
  //   [0,64M):   E (8 x 2048 x 2048 bf16) -- overlaps phase-1 temporaries below
  //   [0,8M):    Kbf | [8,24M): x1t | [24,40M): x2t   (dead before E is written)
  //   [64,80M):  h1n  [80,96M): h2n  [96,112M): h1t
  //   [112M,+64K): rowsum (8 x 2048 f32)
  bf16* E    = (bf16*)(ws);
  bf16* Kbf  = (bf16*)(ws);
  bf16* x1t  = (bf16*)(ws + (8ull << 20));
  bf16* h1n  = (bf16*)(ws + (64ull << 20));
  bf16* h2n  = (bf16*)(ws + (80ull << 20));
  bf16* h1t  = (bf16*)(ws + (96ull << 20));
  float* rowsum = (float*)(ws + (112ull << 20));

  prep<<<dim3(8, 32, 17), 256, 0, stream>>>(x1, x2, km, x1t, Kbf, rowsum);
  gemm_h<<<256, 512, 98304, stream>>>(Kbf, x1t, h1n);
  gemm_score<<<544, 512, 65536, stream>>>(h1n, h2n, E, rowsum, h1t);
  gemm_pv<<<512, 256, 49152, stream>>>(E, h1t, rowsum, out);
}

// Round 13
// 163.259 us; speedup vs baseline: 1.0680x; 1.0170x over previous
//
#include <hip/hip_runtime.h>
#include <hip/hip_bf16.h>

#define S_DIM 2048
#define D_DIM 512
#define B_DIM 8
#define SCALE 0.02209708691207961f  // 1/sqrt(2048)

typedef __hip_bfloat16 bf16;
typedef short bf16x8 __attribute__((ext_vector_type(8)));
typedef float f32x4 __attribute__((ext_vector_type(4)));

__device__ __forceinline__ unsigned short f2b(float f) {
  __hip_bfloat16 h = __float2bfloat16(f);
  return __builtin_bit_cast(unsigned short, h);
}
__device__ __forceinline__ float b2f(unsigned short s) {
  return __bfloat162float(__builtin_bit_cast(__hip_bfloat16, s));
}

__device__ __forceinline__ void load_lds16(const void* g, void* l) {
  __builtin_amdgcn_global_load_lds((const __attribute__((address_space(1))) void*)g,
                                   (__attribute__((address_space(3))) void*)l, 16, 0, 0);
}

// ---------------- fused prep: x1,x2 transpose+convert | K convert | rowsum zero --------
__global__ void prep(const float* __restrict__ x1, const float* __restrict__ x2,
                     const float* __restrict__ km,
                     bf16* __restrict__ xt, bf16* __restrict__ Kbf,
                     float* __restrict__ rowsum) {
  const int z = blockIdx.z;
  const int tid = threadIdx.x;
  if (z == 16) {
    const int bid = blockIdx.y * 8 + blockIdx.x;   // 0..255
    const float4* p = (const float4*)km;
    bf16x8* o = (bf16x8*)Kbf;
#pragma unroll
    for (int it = 0; it < 8; it++) {
      int i = bid * 2048 + it * 256 + tid;
      float4 a = p[2 * i], b = p[2 * i + 1];
      bf16x8 r;
      r[0] = f2b(a.x); r[1] = f2b(a.y); r[2] = f2b(a.z); r[3] = f2b(a.w);
      r[4] = f2b(b.x); r[5] = f2b(b.y); r[6] = f2b(b.z); r[7] = f2b(b.w);
      o[i] = r;
    }
    if (bid < 8) {
      float4 zf = {0.0f, 0.0f, 0.0f, 0.0f};
      float4* rp = (float4*)(rowsum + bid * 2048);
      rp[tid * 2] = zf;
      rp[tid * 2 + 1] = zf;
    }
    return;
  }
  __shared__ unsigned short t[64][66];
  const float* in = (z < 8 ? x1 : x2) + (size_t)(z & 7) * (S_DIM * D_DIM);
  bf16* ob = xt + (size_t)z * (size_t)(D_DIM * S_DIM);
  const int r0 = blockIdx.y * 64;   // S
  const int c0 = blockIdx.x * 64;   // D
  const int lr = tid >> 4, lq = tid & 15;
#pragma unroll
  for (int i = 0; i < 4; i++) {
    int r = i * 16 + lr;
    float4 v = *(const float4*)(in + (size_t)(r0 + r) * D_DIM + c0 + lq * 4);
    t[lq * 4 + 0][r] = f2b(v.x);
    t[lq * 4 + 1][r] = f2b(v.y);
    t[lq * 4 + 2][r] = f2b(v.z);
    t[lq * 4 + 3][r] = f2b(v.w);
  }
  __syncthreads();
#pragma unroll
  for (int j = 0; j < 4; j++) {
    int d = j * 16 + lr;
    const unsigned short* p = &t[d][lq * 4];
    uint2 u;
    u.x = (unsigned)p[0] | ((unsigned)p[1] << 16);
    u.y = (unsigned)p[2] | ((unsigned)p[3] << 16);
    *(uint2*)(ob + (size_t)(c0 + d) * S_DIM + r0 + lq * 4) = u;
  }
}

// ---------------- h-GEMM v4: 256x256xBK=64, double-buffer, 1 barrier/step --------------
// H[item][s][d] = sum_t A[s][t]*X[item][d][t]. 8 waves (2m x 4n), per-wave 128x64,
// 64 MFMA/step, 32 steps. LDS 128KB: A bufs 2x32KB @0, B bufs 2x32KB @64KB.
// Spill-free by construction: per-kk af[8]+bfv[4] = 48 held VGPRs (= R4's proven
// liveness); 12 base read-offsets, kk-half via ^64 (slot bit-6 XOR, exact).
// Sync: [barrier] stage(t+1) -> reads+MFMA of buf t -> vmcnt(0) [barrier].
// Race-freedom: buf (t+1)&1 holds tile t-1, whose ds_reads every wave consumed
// (compiler lgkm waits before MFMA) before passing the end-of-(t-1) barrier.
// Swizzle (R9-verified at BK=64, 0 conflicts): LDS[row][slot16B] = G[row][slot^(row&7)].
__global__ __launch_bounds__(512, 1) void gemm_h(
    const bf16* __restrict__ A, const bf16* __restrict__ X, bf16* __restrict__ H) {
  extern __shared__ char smem[];
  const int pid = blockIdx.x;
  const int mt = pid & 7;              // XCD-pinned A panel
  const int r_ = pid >> 3;
  const int ntile = r_ & 1;
  const int item = r_ >> 1;            // 0..15
  const int m0 = mt * 256, n0 = ntile * 256;
  const bf16* Xi = X + (size_t)item * (D_DIM * S_DIM);
  bf16* Hi = H + (size_t)item * (S_DIM * D_DIM);

  const int tid = threadIdx.x;
  const int w = tid >> 6, L = tid & 63;
  const int l15 = L & 15, lhi = L >> 4;
  const int wr = w >> 2, wn = w & 3;

  // staging: row = ld*64 + (tid>>3); src slot pre-swizzled (tid&7)^((tid>>3)&7)
  const int srow = tid >> 3;                       // 0..63
  const int sslot = ((tid & 7) ^ (srow & 7)) * 8;  // elements
  const bf16* pA[4];
  const bf16* pB[4];
#pragma unroll
  for (int ld = 0; ld < 4; ld++) {
    pA[ld] = A + (size_t)(m0 + ld * 64 + srow) * 2048 + sslot;
    pB[ld] = Xi + (size_t)(n0 + ld * 64 + srow) * 2048 + sslot;
  }

  auto stage = [&](int t) {
    char* dA = smem + (t & 1) * 32768 + w * 1024;          // wave-uniform base
    char* dB = smem + 65536 + (t & 1) * 32768 + w * 1024;
    const int ko = t * 64;
#pragma unroll
    for (int ld = 0; ld < 4; ld++) {
      load_lds16(pA[ld] + ko, dA + ld * 8192);
      load_lds16(pB[ld] + ko, dB + ld * 8192);
    }
  };

  // read offsets (kk=0); kk=1 = offset ^ 64 (slot bit-2 -> byte bit-6, slot-only bit)
  const int xsw = l15 & 7;
  int offA0[8], offB0[4];
#pragma unroll
  for (int m = 0; m < 8; m++)
    offA0[m] = (wr * 128 + m * 16 + l15) * 128 + ((lhi ^ xsw) << 4);
#pragma unroll
  for (int n = 0; n < 4; n++)
    offB0[n] = (wn * 64 + n * 16 + l15) * 128 + ((lhi ^ xsw) << 4);

  f32x4 acc[8][4];
#pragma unroll
  for (int m = 0; m < 8; m++)
#pragma unroll
    for (int n = 0; n < 4; n++) acc[m][n] = (f32x4){0, 0, 0, 0};

  stage(0);
  asm volatile("s_waitcnt vmcnt(0)" ::: "memory");
  __builtin_amdgcn_s_barrier();
  asm volatile("" ::: "memory");

#pragma unroll 1
  for (int t = 0; t < 32; ++t) {
    if (t + 1 < 32) stage(t + 1);
    const char* bA = smem + (t & 1) * 32768;
    const char* bB = smem + 65536 + (t & 1) * 32768;
#pragma unroll
    for (int kk = 0; kk < 2; kk++) {
      bf16x8 af[8], bfv[4];
#pragma unroll
      for (int m = 0; m < 8; m++) af[m] = *(const bf16x8*)(bA + (offA0[m] ^ (kk << 6)));
#pragma unroll
      for (int n = 0; n < 4; n++) bfv[n] = *(const bf16x8*)(bB + (offB0[n] ^ (kk << 6)));
      __builtin_amdgcn_s_setprio(1);
#pragma unroll
      for (int m = 0; m < 8; m++)
#pragma unroll
        for (int n = 0; n < 4; n++)
          acc[m][n] = __builtin_amdgcn_mfma_f32_16x16x32_bf16(bfv[n], af[m], acc[m][n], 0, 0, 0);
      __builtin_amdgcn_s_setprio(0);
    }
    asm volatile("s_waitcnt vmcnt(0)" ::: "memory");   // stage(t+1) landed (issued ~full step ago)
    __builtin_amdgcn_s_barrier();
    asm volatile("" ::: "memory");
  }

  // swapped-operand C layout -> 8B packed stores
#pragma unroll
  for (int m = 0; m < 8; m++) {
    int grow = m0 + wr * 128 + m * 16 + l15;
#pragma unroll
    for (int n = 0; n < 4; n++) {
      int gcol = n0 + wn * 64 + n * 16 + lhi * 4;
      uint2 u;
      u.x = ((unsigned)f2b(acc[m][n][1]) << 16) | f2b(acc[m][n][0]);
      u.y = ((unsigned)f2b(acc[m][n][3]) << 16) | f2b(acc[m][n][2]);
      *(uint2*)(Hi + (size_t)grow * D_DIM + gcol) = u;
    }
  }
}

// ---------------- score GEMM + fused h1n->h1t transpose (R12-verbatim) ----------------
__global__ __launch_bounds__(512, 2) void gemm_score(
    const bf16* __restrict__ H1, const bf16* __restrict__ H2,
    bf16* __restrict__ E, float* __restrict__ rowsum, bf16* __restrict__ H1T) {
  extern __shared__ char smem[];
  const int pid = blockIdx.x;
  const int tid = threadIdx.x;

  if (pid >= 288) {
    const int tb = pid - 288;                 // 0..255
    const int half = tid >> 8;                // 0/1
    const int t5 = tid & 255;
    unsigned short (*tl)[66] = (unsigned short (*)[66])(smem + half * 8448);
    const int lr = t5 >> 4, lq = t5 & 15;
#pragma unroll 1
    for (int i = 0; i < 4; i++) {
      const int tile = tb * 8 + half * 4 + i;   // 0..2047
      const int z = tile >> 8;
      const int rem = tile & 255;
      const int r0 = (rem >> 3) * 64;           // S
      const int c0 = (rem & 7) * 64;            // D
      const bf16* ib = H1 + (size_t)z * (S_DIM * D_DIM);
      bf16* ob = H1T + (size_t)z * (S_DIM * D_DIM);
#pragma unroll
      for (int j = 0; j < 4; j++) {
        int r = j * 16 + lr;
        uint2 v = *(const uint2*)(ib + (size_t)(r0 + r) * D_DIM + c0 + lq * 4);
        tl[lq * 4 + 0][r] = (unsigned short)(v.x & 0xffff);
        tl[lq * 4 + 1][r] = (unsigned short)(v.x >> 16);
        tl[lq * 4 + 2][r] = (unsigned short)(v.y & 0xffff);
        tl[lq * 4 + 3][r] = (unsigned short)(v.y >> 16);
      }
      __syncthreads();
#pragma unroll
      for (int j = 0; j < 4; j++) {
        int d = j * 16 + lr;
        const unsigned short* p = &tl[d][lq * 4];
        uint2 u;
        u.x = (unsigned)p[0] | ((unsigned)p[1] << 16);
        u.y = (unsigned)p[2] | ((unsigned)p[3] << 16);
        *(uint2*)(ob + (size_t)(c0 + d) * S_DIM + r0 + lq * 4) = u;
      }
      __syncthreads();
    }
    return;
  }

  const int b = pid & 7;           // batch pinned to XCD
  const int tri = pid >> 3;        // 0..35
  int mt = (int)((sqrtf(8.0f * (float)tri + 1.0f) - 1.0f) * 0.5f);
  while ((mt + 1) * (mt + 2) / 2 <= tri) mt++;
  while (mt * (mt + 1) / 2 > tri) mt--;
  const int nt = tri - mt * (mt + 1) / 2;
  const int m0 = mt * 256, n0 = nt * 256;
  const bool diag = (mt == nt);
  const bf16* Ab = H1 + (size_t)b * S_DIM * D_DIM;
  const bf16* Bb = H2 + (size_t)b * S_DIM * D_DIM;
  bf16* Eb = E + (size_t)b * S_DIM * S_DIM;
  float* rs = rowsum + b * S_DIM;

  const int w = tid >> 6, L = tid & 63;
  const int l15 = L & 15, lhi = L >> 4;
  const int wr = w >> 2, wn = w & 3;

  const int srow = tid >> 2;
  const int sslot = ((tid & 3) ^ ((tid >> 3) & 3)) * 8;
  const bf16* pA[2];
  const bf16* pB[2];
#pragma unroll
  for (int ld = 0; ld < 2; ld++) {
    pA[ld] = Ab + (size_t)(m0 + ld * 128 + srow) * D_DIM + sslot;
    pB[ld] = Bb + (size_t)(n0 + ld * 128 + srow) * D_DIM + sslot;
  }

  auto stage = [&](int t) {
    char* dA = smem + (t & 1) * 16384;
    char* dB = smem + 32768 + (t & 1) * 16384;
#pragma unroll
    for (int ld = 0; ld < 2; ld++)
      load_lds16(pA[ld] + t * 32, dA + ld * 8192 + w * 1024);
#pragma unroll
    for (int ld = 0; ld < 2; ld++)
      load_lds16(pB[ld] + t * 32, dB + ld * 8192 + w * 1024);
  };

  const int xo = (lhi ^ ((l15 >> 1) & 3)) << 4;
  int offA[8], offB[4];
#pragma unroll
  for (int m = 0; m < 8; m++) offA[m] = (wr * 128 + m * 16 + l15) * 64 + xo;
#pragma unroll
  for (int n = 0; n < 4; n++) offB[n] = (wn * 64 + n * 16 + l15) * 64 + xo;

  f32x4 acc[8][4];
#pragma unroll
  for (int m = 0; m < 8; m++)
#pragma unroll
    for (int n = 0; n < 4; n++) acc[m][n] = (f32x4){0, 0, 0, 0};

  stage(0);
#pragma unroll 2
  for (int t = 0; t < 16; ++t) {
    __syncthreads();
    if (t + 1 < 16) stage(t + 1);
    const char* bA = smem + (t & 1) * 16384;
    const char* bB = smem + 32768 + (t & 1) * 16384;
    bf16x8 af[8], bfv[4];
#pragma unroll
    for (int m = 0; m < 8; m++) af[m] = *(const bf16x8*)(bA + offA[m]);
#pragma unroll
    for (int n = 0; n < 4; n++) bfv[n] = *(const bf16x8*)(bB + offB[n]);
    __builtin_amdgcn_s_setprio(1);
#pragma unroll
    for (int m = 0; m < 8; m++)
#pragma unroll
      for (int n = 0; n < 4; n++)
        acc[m][n] = __builtin_amdgcn_mfma_f32_16x16x32_bf16(bfv[n], af[m], acc[m][n], 0, 0, 0);
    __builtin_amdgcn_s_setprio(0);
  }

#pragma unroll
  for (int m = 0; m < 8; m++) {
    int sg = m0 + wr * 128 + m * 16 + l15;
    float rp = 0.0f;
#pragma unroll
    for (int n = 0; n < 4; n++) {
      int tg0 = n0 + wn * 64 + n * 16 + lhi * 4;
      unsigned short e[4];
#pragma unroll
      for (int r = 0; r < 4; r++) {
        float v = (!diag || (tg0 + r) <= sg) ? __expf(acc[m][n][r] * SCALE) : 0.0f;
        e[r] = f2b(v);
        rp += b2f(e[r]);
      }
      uint2 u;
      u.x = ((unsigned)e[1] << 16) | e[0];
      u.y = ((unsigned)e[3] << 16) | e[2];
      *(uint2*)(Eb + (size_t)sg * S_DIM + tg0) = u;
    }
    rp += __shfl_xor(rp, 16);
    rp += __shfl_xor(rp, 32);
    if (lhi == 0) atomicAdd(rs + sg, rp);
  }
}

// ---------------- PV GEMM (R8-verbatim): triple-buffer 128x128xBK=32 ------------------
__global__ __launch_bounds__(256, 2) void gemm_pv(
    const bf16* __restrict__ E, const bf16* __restrict__ H1T,
    const float* __restrict__ rowsum, float* __restrict__ out) {
  extern __shared__ char smem[];
  const int pid = blockIdx.x;
  const int b = pid & 7;
  const int r_ = pid >> 3;
  const int nt = r_ & 3;
  const int mb = r_ >> 2;
  const int mt = (mb < 8) ? 2 * mb : 31 - 2 * mb;
  const int m0 = mt * 128, n0 = nt * 128;
  const int NT = (mt + 1) * 4;
  const bf16* Ab = E + (size_t)b * S_DIM * S_DIM + (size_t)m0 * S_DIM;
  const bf16* Bb = H1T + (size_t)b * D_DIM * S_DIM + (size_t)n0 * S_DIM;
  const float* rs = rowsum + b * S_DIM;
  float* Cb = out + (size_t)b * S_DIM * D_DIM;

  const int tid = threadIdx.x;
  const int w = tid >> 6, L = tid & 63;
  const int l15 = L & 15, lhi = L >> 4;
  const int wr = w >> 1, wc = w & 1;

  const int srow = tid >> 2;
  const int sslot = ((tid & 3) ^ ((tid >> 3) & 3)) * 8;
  const bf16* pA[2];
  const bf16* pB[2];
#pragma unroll
  for (int ld = 0; ld < 2; ld++) {
    pA[ld] = Ab + (size_t)(ld * 64 + srow) * S_DIM + sslot;
    pB[ld] = Bb + (size_t)(ld * 64 + srow) * S_DIM + sslot;
  }

  char* A0 = smem;          char* A1 = smem + 8192;   char* A2 = smem + 16384;
  char* B0 = smem + 24576;  char* B1 = smem + 32768;  char* B2 = smem + 40960;

  auto stage = [&](int t2, char* dA, char* dB) {
#pragma unroll
    for (int ld = 0; ld < 2; ld++)
      load_lds16(pA[ld] + t2 * 32, dA + ld * 4096 + w * 1024);
#pragma unroll
    for (int ld = 0; ld < 2; ld++)
      load_lds16(pB[ld] + t2 * 32, dB + ld * 4096 + w * 1024);
  };

  const int xo = (lhi ^ ((l15 >> 1) & 3)) << 4;
  int offA[4], offB[4];
#pragma unroll
  for (int m = 0; m < 4; m++) offA[m] = (wr * 64 + m * 16 + l15) * 64 + xo;
#pragma unroll
  for (int n = 0; n < 4; n++) offB[n] = (wc * 64 + n * 16 + l15) * 64 + xo;

  f32x4 acc[4][4];
#pragma unroll
  for (int m = 0; m < 4; m++)
#pragma unroll
    for (int n = 0; n < 4; n++) acc[m][n] = (f32x4){0, 0, 0, 0};

  stage(0, A0, B0);
  stage(1, A1, B1);

#pragma unroll 1
  for (int t = 0; t < NT; ++t) {
    if (t < NT - 1) asm volatile("s_waitcnt vmcnt(4)" ::: "memory");
    else            asm volatile("s_waitcnt vmcnt(0)" ::: "memory");
    __builtin_amdgcn_s_barrier();
    asm volatile("" ::: "memory");
    if (t + 2 < NT) stage(t + 2, A2, B2);

    bf16x8 af[4], bfv[4];
#pragma unroll
    for (int m = 0; m < 4; m++) af[m] = *(const bf16x8*)(A0 + offA[m]);
#pragma unroll
    for (int n = 0; n < 4; n++) bfv[n] = *(const bf16x8*)(B0 + offB[n]);
    __builtin_amdgcn_s_setprio(1);
#pragma unroll
    for (int m = 0; m < 4; m++)
#pragma unroll
      for (int n = 0; n < 4; n++)
        acc[m][n] = __builtin_amdgcn_mfma_f32_16x16x32_bf16(bfv[n], af[m], acc[m][n], 0, 0, 0);
    __builtin_amdgcn_s_setprio(0);

    char* tA = A0; A0 = A1; A1 = A2; A2 = tA;
    char* tB = B0; B0 = B1; B1 = B2; B2 = tB;
  }

#pragma unroll
  for (int m = 0; m < 4; m++) {
    int sg = m0 + wr * 64 + m * 16 + l15;
    float inv = 1.0f / rs[sg];
#pragma unroll
    for (int n = 0; n < 4; n++) {
      int gcol = n0 + wc * 64 + n * 16 + lhi * 4;
      float4 o;
      o.x = acc[m][n][0] * inv;
      o.y = acc[m][n][1] * inv;
      o.z = acc[m][n][2] * inv;
      o.w = acc[m][n][3] * inv;
      *(float4*)(Cb + (size_t)sg * D_DIM + gcol) = o;
    }
  }
}

extern "C" void kernel_launch(void* const* d_in, const int* in_sizes, int n_in,
                              void* d_out, int out_size, void* d_ws, size_t ws_size,
                              hipStream_t stream) {
  const float* x1 = (const float*)d_in[0];
  const float* x2 = (const float*)d_in[1];
  const float* km = (const float*)d_in[2];
  float* out = (float*)d_out;
  char* ws = (char*)d_ws;
  // ws layout (bytes):
  //   [0,64M):   E (8 x 2048 x 2048 bf16) -- overlaps phase-1 temporaries below
  //   [0,8M):    Kbf | [8,24M): x1t | [24,40M): x2t   (dead before E is written)
  //   [64,80M):  h1n  [80,96M): h2n  [96,112M): h1t
  //   [112M,+64K): rowsum (8 x 2048 f32)
  bf16* E    = (bf16*)(ws);
  bf16* Kbf  = (bf16*)(ws);
  bf16* x1t  = (bf16*)(ws + (8ull << 20));
  bf16* h1n  = (bf16*)(ws + (64ull << 20));
  bf16* h2n  = (bf16*)(ws + (80ull << 20));
  bf16* h1t  = (bf16*)(ws + (96ull << 20));
  float* rowsum = (float*)(ws + (112ull << 20));

  prep<<<dim3(8, 32, 17), 256, 0, stream>>>(x1, x2, km, x1t, Kbf, rowsum);
  gemm_h<<<256, 512, 131072, stream>>>(Kbf, x1t, h1n);
  gemm_score<<<544, 512, 65536, stream>>>(h1n, h2n, E, rowsum, h1t);
  gemm_pv<<<512, 256, 49152, stream>>>(E, h1t, rowsum, out);
}

// Round 14
// 160.968 us; speedup vs baseline: 1.0832x; 1.0142x over previous
//
#include <hip/hip_runtime.h>
#include <hip/hip_bf16.h>

#define S_DIM 2048
#define D_DIM 512
#define B_DIM 8
#define SCALE 0.02209708691207961f  // 1/sqrt(2048)

typedef __hip_bfloat16 bf16;
typedef short bf16x8 __attribute__((ext_vector_type(8)));
typedef float f32x4 __attribute__((ext_vector_type(4)));

__device__ __forceinline__ unsigned short f2b(float f) {
  __hip_bfloat16 h = __float2bfloat16(f);
  return __builtin_bit_cast(unsigned short, h);
}
__device__ __forceinline__ float b2f(unsigned short s) {
  return __bfloat162float(__builtin_bit_cast(__hip_bfloat16, s));
}

__device__ __forceinline__ void load_lds16(const void* g, void* l) {
  __builtin_amdgcn_global_load_lds((const __attribute__((address_space(1))) void*)g,
                                   (__attribute__((address_space(3))) void*)l, 16, 0, 0);
}

// ---------------- fused prep: x1,x2 transpose+convert | K convert | rowsum zero --------
__global__ void prep(const float* __restrict__ x1, const float* __restrict__ x2,
                     const float* __restrict__ km,
                     bf16* __restrict__ xt, bf16* __restrict__ Kbf,
                     float* __restrict__ rowsum) {
  const int z = blockIdx.z;
  const int tid = threadIdx.x;
  if (z == 16) {
    const int bid = blockIdx.y * 8 + blockIdx.x;   // 0..255
    const float4* p = (const float4*)km;
    bf16x8* o = (bf16x8*)Kbf;
#pragma unroll
    for (int it = 0; it < 8; it++) {
      int i = bid * 2048 + it * 256 + tid;
      float4 a = p[2 * i], b = p[2 * i + 1];
      bf16x8 r;
      r[0] = f2b(a.x); r[1] = f2b(a.y); r[2] = f2b(a.z); r[3] = f2b(a.w);
      r[4] = f2b(b.x); r[5] = f2b(b.y); r[6] = f2b(b.z); r[7] = f2b(b.w);
      o[i] = r;
    }
    if (bid < 8) {
      float4 zf = {0.0f, 0.0f, 0.0f, 0.0f};
      float4* rp = (float4*)(rowsum + bid * 2048);
      rp[tid * 2] = zf;
      rp[tid * 2 + 1] = zf;
    }
    return;
  }
  __shared__ unsigned short t[64][66];
  const float* in = (z < 8 ? x1 : x2) + (size_t)(z & 7) * (S_DIM * D_DIM);
  bf16* ob = xt + (size_t)z * (size_t)(D_DIM * S_DIM);
  const int r0 = blockIdx.y * 64;   // S
  const int c0 = blockIdx.x * 64;   // D
  const int lr = tid >> 4, lq = tid & 15;
#pragma unroll
  for (int i = 0; i < 4; i++) {
    int r = i * 16 + lr;
    float4 v = *(const float4*)(in + (size_t)(r0 + r) * D_DIM + c0 + lq * 4);
    t[lq * 4 + 0][r] = f2b(v.x);
    t[lq * 4 + 1][r] = f2b(v.y);
    t[lq * 4 + 2][r] = f2b(v.z);
    t[lq * 4 + 3][r] = f2b(v.w);
  }
  __syncthreads();
#pragma unroll
  for (int j = 0; j < 4; j++) {
    int d = j * 16 + lr;
    const unsigned short* p = &t[d][lq * 4];
    uint2 u;
    u.x = (unsigned)p[0] | ((unsigned)p[1] << 16);
    u.y = (unsigned)p[2] | ((unsigned)p[3] << 16);
    *(uint2*)(ob + (size_t)(c0 + d) * S_DIM + r0 + lq * 4) = u;
  }
}

// ---------------- h-GEMM v4 (R13-verbatim, 68.6us): 256x256xBK=64, dbuf ----------------
__global__ __launch_bounds__(512, 1) void gemm_h(
    const bf16* __restrict__ A, const bf16* __restrict__ X, bf16* __restrict__ H) {
  extern __shared__ char smem[];
  const int pid = blockIdx.x;
  const int mt = pid & 7;              // XCD-pinned A panel
  const int r_ = pid >> 3;
  const int ntile = r_ & 1;
  const int item = r_ >> 1;            // 0..15
  const int m0 = mt * 256, n0 = ntile * 256;
  const bf16* Xi = X + (size_t)item * (D_DIM * S_DIM);
  bf16* Hi = H + (size_t)item * (S_DIM * D_DIM);

  const int tid = threadIdx.x;
  const int w = tid >> 6, L = tid & 63;
  const int l15 = L & 15, lhi = L >> 4;
  const int wr = w >> 2, wn = w & 3;

  const int srow = tid >> 3;                       // 0..63
  const int sslot = ((tid & 7) ^ (srow & 7)) * 8;  // elements
  const bf16* pA[4];
  const bf16* pB[4];
#pragma unroll
  for (int ld = 0; ld < 4; ld++) {
    pA[ld] = A + (size_t)(m0 + ld * 64 + srow) * 2048 + sslot;
    pB[ld] = Xi + (size_t)(n0 + ld * 64 + srow) * 2048 + sslot;
  }

  auto stage = [&](int t) {
    char* dA = smem + (t & 1) * 32768 + w * 1024;
    char* dB = smem + 65536 + (t & 1) * 32768 + w * 1024;
    const int ko = t * 64;
#pragma unroll
    for (int ld = 0; ld < 4; ld++) {
      load_lds16(pA[ld] + ko, dA + ld * 8192);
      load_lds16(pB[ld] + ko, dB + ld * 8192);
    }
  };

  const int xsw = l15 & 7;
  int offA0[8], offB0[4];
#pragma unroll
  for (int m = 0; m < 8; m++)
    offA0[m] = (wr * 128 + m * 16 + l15) * 128 + ((lhi ^ xsw) << 4);
#pragma unroll
  for (int n = 0; n < 4; n++)
    offB0[n] = (wn * 64 + n * 16 + l15) * 128 + ((lhi ^ xsw) << 4);

  f32x4 acc[8][4];
#pragma unroll
  for (int m = 0; m < 8; m++)
#pragma unroll
    for (int n = 0; n < 4; n++) acc[m][n] = (f32x4){0, 0, 0, 0};

  stage(0);
  asm volatile("s_waitcnt vmcnt(0)" ::: "memory");
  __builtin_amdgcn_s_barrier();
  asm volatile("" ::: "memory");

#pragma unroll 1
  for (int t = 0; t < 32; ++t) {
    if (t + 1 < 32) stage(t + 1);
    const char* bA = smem + (t & 1) * 32768;
    const char* bB = smem + 65536 + (t & 1) * 32768;
#pragma unroll
    for (int kk = 0; kk < 2; kk++) {
      bf16x8 af[8], bfv[4];
#pragma unroll
      for (int m = 0; m < 8; m++) af[m] = *(const bf16x8*)(bA + (offA0[m] ^ (kk << 6)));
#pragma unroll
      for (int n = 0; n < 4; n++) bfv[n] = *(const bf16x8*)(bB + (offB0[n] ^ (kk << 6)));
      __builtin_amdgcn_s_setprio(1);
#pragma unroll
      for (int m = 0; m < 8; m++)
#pragma unroll
        for (int n = 0; n < 4; n++)
          acc[m][n] = __builtin_amdgcn_mfma_f32_16x16x32_bf16(bfv[n], af[m], acc[m][n], 0, 0, 0);
      __builtin_amdgcn_s_setprio(0);
    }
    asm volatile("s_waitcnt vmcnt(0)" ::: "memory");
    __builtin_amdgcn_s_barrier();
    asm volatile("" ::: "memory");
  }

#pragma unroll
  for (int m = 0; m < 8; m++) {
    int grow = m0 + wr * 128 + m * 16 + l15;
#pragma unroll
    for (int n = 0; n < 4; n++) {
      int gcol = n0 + wn * 64 + n * 16 + lhi * 4;
      uint2 u;
      u.x = ((unsigned)f2b(acc[m][n][1]) << 16) | f2b(acc[m][n][0]);
      u.y = ((unsigned)f2b(acc[m][n][3]) << 16) | f2b(acc[m][n][2]);
      *(uint2*)(Hi + (size_t)grow * D_DIM + gcol) = u;
    }
  }
}

// ---------------- score GEMM + fused h1n->h1t transpose (R12-verbatim) ----------------
__global__ __launch_bounds__(512, 2) void gemm_score(
    const bf16* __restrict__ H1, const bf16* __restrict__ H2,
    bf16* __restrict__ E, float* __restrict__ rowsum, bf16* __restrict__ H1T) {
  extern __shared__ char smem[];
  const int pid = blockIdx.x;
  const int tid = threadIdx.x;

  if (pid >= 288) {
    const int tb = pid - 288;                 // 0..255
    const int half = tid >> 8;                // 0/1
    const int t5 = tid & 255;
    unsigned short (*tl)[66] = (unsigned short (*)[66])(smem + half * 8448);
    const int lr = t5 >> 4, lq = t5 & 15;
#pragma unroll 1
    for (int i = 0; i < 4; i++) {
      const int tile = tb * 8 + half * 4 + i;   // 0..2047
      const int z = tile >> 8;
      const int rem = tile & 255;
      const int r0 = (rem >> 3) * 64;           // S
      const int c0 = (rem & 7) * 64;            // D
      const bf16* ib = H1 + (size_t)z * (S_DIM * D_DIM);
      bf16* ob = H1T + (size_t)z * (S_DIM * D_DIM);
#pragma unroll
      for (int j = 0; j < 4; j++) {
        int r = j * 16 + lr;
        uint2 v = *(const uint2*)(ib + (size_t)(r0 + r) * D_DIM + c0 + lq * 4);
        tl[lq * 4 + 0][r] = (unsigned short)(v.x & 0xffff);
        tl[lq * 4 + 1][r] = (unsigned short)(v.x >> 16);
        tl[lq * 4 + 2][r] = (unsigned short)(v.y & 0xffff);
        tl[lq * 4 + 3][r] = (unsigned short)(v.y >> 16);
      }
      __syncthreads();
#pragma unroll
      for (int j = 0; j < 4; j++) {
        int d = j * 16 + lr;
        const unsigned short* p = &tl[d][lq * 4];
        uint2 u;
        u.x = (unsigned)p[0] | ((unsigned)p[1] << 16);
        u.y = (unsigned)p[2] | ((unsigned)p[3] << 16);
        *(uint2*)(ob + (size_t)(c0 + d) * S_DIM + r0 + lq * 4) = u;
      }
      __syncthreads();
    }
    return;
  }

  const int b = pid & 7;           // batch pinned to XCD
  const int tri = pid >> 3;        // 0..35
  int mt = (int)((sqrtf(8.0f * (float)tri + 1.0f) - 1.0f) * 0.5f);
  while ((mt + 1) * (mt + 2) / 2 <= tri) mt++;
  while (mt * (mt + 1) / 2 > tri) mt--;
  const int nt = tri - mt * (mt + 1) / 2;
  const int m0 = mt * 256, n0 = nt * 256;
  const bool diag = (mt == nt);
  const bf16* Ab = H1 + (size_t)b * S_DIM * D_DIM;
  const bf16* Bb = H2 + (size_t)b * S_DIM * D_DIM;
  bf16* Eb = E + (size_t)b * S_DIM * S_DIM;
  float* rs = rowsum + b * S_DIM;

  const int w = tid >> 6, L = tid & 63;
  const int l15 = L & 15, lhi = L >> 4;
  const int wr = w >> 2, wn = w & 3;

  const int srow = tid >> 2;
  const int sslot = ((tid & 3) ^ ((tid >> 3) & 3)) * 8;
  const bf16* pA[2];
  const bf16* pB[2];
#pragma unroll
  for (int ld = 0; ld < 2; ld++) {
    pA[ld] = Ab + (size_t)(m0 + ld * 128 + srow) * D_DIM + sslot;
    pB[ld] = Bb + (size_t)(n0 + ld * 128 + srow) * D_DIM + sslot;
  }

  auto stage = [&](int t) {
    char* dA = smem + (t & 1) * 16384;
    char* dB = smem + 32768 + (t & 1) * 16384;
#pragma unroll
    for (int ld = 0; ld < 2; ld++)
      load_lds16(pA[ld] + t * 32, dA + ld * 8192 + w * 1024);
#pragma unroll
    for (int ld = 0; ld < 2; ld++)
      load_lds16(pB[ld] + t * 32, dB + ld * 8192 + w * 1024);
  };

  const int xo = (lhi ^ ((l15 >> 1) & 3)) << 4;
  int offA[8], offB[4];
#pragma unroll
  for (int m = 0; m < 8; m++) offA[m] = (wr * 128 + m * 16 + l15) * 64 + xo;
#pragma unroll
  for (int n = 0; n < 4; n++) offB[n] = (wn * 64 + n * 16 + l15) * 64 + xo;

  f32x4 acc[8][4];
#pragma unroll
  for (int m = 0; m < 8; m++)
#pragma unroll
    for (int n = 0; n < 4; n++) acc[m][n] = (f32x4){0, 0, 0, 0};

  stage(0);
#pragma unroll 2
  for (int t = 0; t < 16; ++t) {
    __syncthreads();
    if (t + 1 < 16) stage(t + 1);
    const char* bA = smem + (t & 1) * 16384;
    const char* bB = smem + 32768 + (t & 1) * 16384;
    bf16x8 af[8], bfv[4];
#pragma unroll
    for (int m = 0; m < 8; m++) af[m] = *(const bf16x8*)(bA + offA[m]);
#pragma unroll
    for (int n = 0; n < 4; n++) bfv[n] = *(const bf16x8*)(bB + offB[n]);
    __builtin_amdgcn_s_setprio(1);
#pragma unroll
    for (int m = 0; m < 8; m++)
#pragma unroll
      for (int n = 0; n < 4; n++)
        acc[m][n] = __builtin_amdgcn_mfma_f32_16x16x32_bf16(bfv[n], af[m], acc[m][n], 0, 0, 0);
    __builtin_amdgcn_s_setprio(0);
  }

#pragma unroll
  for (int m = 0; m < 8; m++) {
    int sg = m0 + wr * 128 + m * 16 + l15;
    float rp = 0.0f;
#pragma unroll
    for (int n = 0; n < 4; n++) {
      int tg0 = n0 + wn * 64 + n * 16 + lhi * 4;
      unsigned short e[4];
#pragma unroll
      for (int r = 0; r < 4; r++) {
        float v = (!diag || (tg0 + r) <= sg) ? __expf(acc[m][n][r] * SCALE) : 0.0f;
        e[r] = f2b(v);
        rp += b2f(e[r]);
      }
      uint2 u;
      u.x = ((unsigned)e[1] << 16) | e[0];
      u.y = ((unsigned)e[3] << 16) | e[2];
      *(uint2*)(Eb + (size_t)sg * S_DIM + tg0) = u;
    }
    rp += __shfl_xor(rp, 16);
    rp += __shfl_xor(rp, 32);
    if (lhi == 0) atomicAdd(rs + sg, rp);
  }
}

// ---------------- PV GEMM v2: 128x128xBK=64 double-buffer (v4-structure port) ----------
// out[s][d] = (1/rowsum[s]) * sum_t E[s][t]*h1t[d][t]. 4 waves (2m x 2n), per-wave 64x64,
// 32 MFMA/step. LDS 64KB (A 2x16KB @0, B 2x16KB @32KB) -> 2 blocks/CU; causal K-trim
// NT=(mt+1)*2 BK=64 steps; mt scramble pairs (pid, pid+256) at complementary depth
// (sum const 17 tiles/CU). Same swizzle + ^64 kk-half trick as gemm_h v4.
__global__ __launch_bounds__(256, 2) void gemm_pv(
    const bf16* __restrict__ E, const bf16* __restrict__ H1T,
    const float* __restrict__ rowsum, float* __restrict__ out) {
  extern __shared__ char smem[];
  const int pid = blockIdx.x;
  const int b = pid & 7;
  const int r_ = pid >> 3;
  const int nt = r_ & 3;
  const int mb = r_ >> 2;
  const int mt = (mb < 8) ? 2 * mb : 31 - 2 * mb;   // depth-pairing across co-resident blocks
  const int m0 = mt * 128, n0 = nt * 128;
  const int NT = (mt + 1) * 2;     // K-tiles of 64
  const bf16* Ab = E + (size_t)b * S_DIM * S_DIM + (size_t)m0 * S_DIM;
  const bf16* Bb = H1T + (size_t)b * D_DIM * S_DIM + (size_t)n0 * S_DIM;
  const float* rs = rowsum + b * S_DIM;
  float* Cb = out + (size_t)b * S_DIM * D_DIM;

  const int tid = threadIdx.x;
  const int w = tid >> 6, L = tid & 63;
  const int l15 = L & 15, lhi = L >> 4;
  const int wr = w >> 1, wc = w & 1;

  // staging: rows ld*32 + (tid>>3); src slot pre-swizzled (tid&7)^((tid>>3)&7)
  const int srow = tid >> 3;                       // 0..31
  const int sslot = ((tid & 7) ^ (srow & 7)) * 8;  // elements
  const bf16* pA[4];
  const bf16* pB[4];
#pragma unroll
  for (int ld = 0; ld < 4; ld++) {
    pA[ld] = Ab + (size_t)(ld * 32 + srow) * S_DIM + sslot;
    pB[ld] = Bb + (size_t)(ld * 32 + srow) * S_DIM + sslot;
  }

  auto stage = [&](int t) {
    char* dA = smem + (t & 1) * 16384 + w * 1024;
    char* dB = smem + 32768 + (t & 1) * 16384 + w * 1024;
    const int ko = t * 64;
#pragma unroll
    for (int ld = 0; ld < 4; ld++) {
      load_lds16(pA[ld] + ko, dA + ld * 4096);
      load_lds16(pB[ld] + ko, dB + ld * 4096);
    }
  };

  const int xsw = l15 & 7;
  int offA0[4], offB0[4];
#pragma unroll
  for (int m = 0; m < 4; m++)
    offA0[m] = (wr * 64 + m * 16 + l15) * 128 + ((lhi ^ xsw) << 4);
#pragma unroll
  for (int n = 0; n < 4; n++)
    offB0[n] = (wc * 64 + n * 16 + l15) * 128 + ((lhi ^ xsw) << 4);

  f32x4 acc[4][4];
#pragma unroll
  for (int m = 0; m < 4; m++)
#pragma unroll
    for (int n = 0; n < 4; n++) acc[m][n] = (f32x4){0, 0, 0, 0};

  stage(0);
  asm volatile("s_waitcnt vmcnt(0)" ::: "memory");
  __builtin_amdgcn_s_barrier();
  asm volatile("" ::: "memory");

#pragma unroll 1
  for (int t = 0; t < NT; ++t) {
    if (t + 1 < NT) stage(t + 1);
    const char* bA = smem + (t & 1) * 16384;
    const char* bB = smem + 32768 + (t & 1) * 16384;
#pragma unroll
    for (int kk = 0; kk < 2; kk++) {
      bf16x8 af[4], bfv[4];
#pragma unroll
      for (int m = 0; m < 4; m++) af[m] = *(const bf16x8*)(bA + (offA0[m] ^ (kk << 6)));
#pragma unroll
      for (int n = 0; n < 4; n++) bfv[n] = *(const bf16x8*)(bB + (offB0[n] ^ (kk << 6)));
      __builtin_amdgcn_s_setprio(1);
#pragma unroll
      for (int m = 0; m < 4; m++)
#pragma unroll
        for (int n = 0; n < 4; n++)
          acc[m][n] = __builtin_amdgcn_mfma_f32_16x16x32_bf16(bfv[n], af[m], acc[m][n], 0, 0, 0);
      __builtin_amdgcn_s_setprio(0);
    }
    asm volatile("s_waitcnt vmcnt(0)" ::: "memory");
    __builtin_amdgcn_s_barrier();
    asm volatile("" ::: "memory");
  }

  // swapped layout: lane -> row m*16+l15, cols n*16+lhi*4+{0..3} -> float4 stores
#pragma unroll
  for (int m = 0; m < 4; m++) {
    int sg = m0 + wr * 64 + m * 16 + l15;
    float inv = 1.0f / rs[sg];
#pragma unroll
    for (int n = 0; n < 4; n++) {
      int gcol = n0 + wc * 64 + n * 16 + lhi * 4;
      float4 o;
      o.x = acc[m][n][0] * inv;
      o.y = acc[m][n][1] * inv;
      o.z = acc[m][n][2] * inv;
      o.w = acc[m][n][3] * inv;
      *(float4*)(Cb + (size_t)sg * D_DIM + gcol) = o;
    }
  }
}

extern "C" void kernel_launch(void* const* d_in, const int* in_sizes, int n_in,
                              void* d_out, int out_size, void* d_ws, size_t ws_size,
                              hipStream_t stream) {
  const float* x1 = (const float*)d_in[0];
  const float* x2 = (const float*)d_in[1];
  const float* km = (const float*)d_in[2];
  float* out = (float*)d_out;
  char* ws = (char*)d_ws;
  // ws layout (bytes):
  //   [0,64M):   E (8 x 2048 x 2048 bf16) -- overlaps phase-1 temporaries below
  //   [0,8M):    Kbf | [8,24M): x1t | [24,40M): x2t   (dead before E is written)
  //   [64,80M):  h1n  [80,96M): h2n  [96,112M): h1t
  //   [112M,+64K): rowsum (8 x 2048 f32)
  bf16* E    = (bf16*)(ws);
  bf16* Kbf  = (bf16*)(ws);
  bf16* x1t  = (bf16*)(ws + (8ull << 20));
  bf16* h1n  = (bf16*)(ws + (64ull << 20));
  bf16* h2n  = (bf16*)(ws + (80ull << 20));
  bf16* h1t  = (bf16*)(ws + (96ull << 20));
  float* rowsum = (float*)(ws + (112ull << 20));

  prep<<<dim3(8, 32, 17), 256, 0, stream>>>(x1, x2, km, x1t, Kbf, rowsum);
  gemm_h<<<256, 512, 131072, stream>>>(Kbf, x1t, h1n);
  gemm_score<<<544, 512, 65536, stream>>>(h1n, h2n, E, rowsum, h1t);
  gemm_pv<<<512, 256, 65536, stream>>>(E, h1t, rowsum, out);
}